// Round 1
// baseline (1855.090 us; speedup 1.0000x reference)
//
#include <hip/hip_runtime.h>
#include <math.h>

#define NEG_SLOPE 0.2f

__device__ inline float lrelu(float x) { return x > 0.f ? x : NEG_SLOPE * x; }
__device__ inline float eluf(float x)  { return x > 0.f ? x : expm1f(x); }

__device__ inline void atomicMaxF(float* addr, float val) {
    int* ai = (int*)addr;
    float old = *addr;
    while (old < val) {
        int assumed = __float_as_int(old);
        int prev = atomicCAS(ai, assumed, __float_as_int(val));
        if (prev == assumed) break;
        old = __int_as_float(prev);
    }
}

// ---------------- GEMM: C[M,N] = A[M,K] @ B[K,N], row-major, N%64==0, K%16==0 ----
template<int BM, int BN, int BK, int TM, int TN>
__global__ void gemm_tiled(const float* __restrict__ A, const float* __restrict__ B,
                           float* __restrict__ C, int M, int N, int K)
{
    __shared__ float As[BK][BM];
    __shared__ float Bs[BK][BN];
    const int tid = threadIdx.x;           // 256 threads
    const int tx = tid & 15, ty = tid >> 4;
    const int rowBase = blockIdx.y * BM;
    const int colBase = blockIdx.x * BN;

    float acc[TM][TN] = {};

    const int aRow = tid >> 2;             // 0..63
    const int aCol = (tid & 3) << 2;       // 0,4,8,12
    const int bRow = tid >> 4;             // 0..15
    const int bCol = (tid & 15) << 2;      // 0..60

    for (int k0 = 0; k0 < K; k0 += BK) {
        {
            int gr = rowBase + aRow;
            float4 v = make_float4(0.f, 0.f, 0.f, 0.f);
            if (gr < M) v = *(const float4*)(A + (size_t)gr * K + k0 + aCol);
            As[aCol + 0][aRow] = v.x;
            As[aCol + 1][aRow] = v.y;
            As[aCol + 2][aRow] = v.z;
            As[aCol + 3][aRow] = v.w;
        }
        {
            float4 v = *(const float4*)(B + (size_t)(k0 + bRow) * N + colBase + bCol);
            *(float4*)&Bs[bRow][bCol] = v;
        }
        __syncthreads();
#pragma unroll
        for (int k = 0; k < BK; ++k) {
            float ra[TM], rb[TN];
#pragma unroll
            for (int i = 0; i < TM; ++i) ra[i] = As[k][ty * TM + i];
#pragma unroll
            for (int j = 0; j < TN; ++j) rb[j] = Bs[k][tx * TN + j];
#pragma unroll
            for (int i = 0; i < TM; ++i)
#pragma unroll
                for (int j = 0; j < TN; ++j)
                    acc[i][j] += ra[i] * rb[j];
        }
        __syncthreads();
    }
#pragma unroll
    for (int i = 0; i < TM; ++i) {
        int gr = rowBase + ty * TM + i;
        if (gr >= M) continue;
        *(float4*)(C + (size_t)gr * N + colBase + tx * TN) =
            make_float4(acc[i][0], acc[i][1], acc[i][2], acc[i][3]);
    }
}

// ---- per-(node,head) attention logits: a_src/a_dst = sum_c h*att ---------------
__global__ void attn_scores(const float* __restrict__ h, const float* __restrict__ att_src,
                            const float* __restrict__ att_dst, float* __restrict__ a_src,
                            float* __restrict__ a_dst, int Nn, int H, int C)
{
    int b = blockIdx.x;            // n*H + head
    int n = b / H, hh = b % H;
    int lane = threadIdx.x;        // 64
    const float* hp = h + (size_t)n * H * C + (size_t)hh * C;
    const float* as = att_src + (size_t)hh * C;
    const float* ad = att_dst + (size_t)hh * C;
    float ss = 0.f, sd = 0.f;
    for (int c = lane; c < C; c += 64) {
        float v = hp[c];
        ss += v * as[c];
        sd += v * ad[c];
    }
#pragma unroll
    for (int off = 32; off > 0; off >>= 1) {
        ss += __shfl_down(ss, off);
        sd += __shfl_down(sd, off);
    }
    if (lane == 0) { a_src[b] = ss; a_dst[b] = sd; }
}

__global__ void fill_f(float* __restrict__ p, float v, int n)
{
    int i = blockIdx.x * blockDim.x + threadIdx.x;
    if (i < n) p[i] = v;
}

// edges are [0,E) from edge_index plus N self-loops appended
__global__ void edge_max_k(const int* __restrict__ src, const int* __restrict__ dst,
                           const float* __restrict__ a_src, const float* __restrict__ a_dst,
                           float* __restrict__ amax, int E, int Nn, int H)
{
    int e = blockIdx.x * blockDim.x + threadIdx.x;
    if (e >= E + Nn) return;
    int s, d;
    if (e < E) { s = src[e]; d = dst[e]; } else { s = e - E; d = s; }
    for (int h = 0; h < H; ++h) {
        float al = lrelu(a_src[s * H + h] + a_dst[d * H + h]);
        atomicMaxF(&amax[d * H + h], al);
    }
}

__global__ void edge_exp_k(const int* __restrict__ src, const int* __restrict__ dst,
                           const float* __restrict__ a_src, const float* __restrict__ a_dst,
                           const float* __restrict__ amax, float* __restrict__ w,
                           float* __restrict__ denom, int E, int Nn, int H)
{
    int e = blockIdx.x * blockDim.x + threadIdx.x;
    if (e >= E + Nn) return;
    int s, d;
    if (e < E) { s = src[e]; d = dst[e]; } else { s = e - E; d = s; }
    for (int h = 0; h < H; ++h) {
        float al = lrelu(a_src[s * H + h] + a_dst[d * H + h]);
        float ex = expf(al - amax[d * H + h]);
        w[(size_t)e * H + h] = ex;
        atomicAdd(&denom[d * H + h], ex);
    }
}

// one block per edge, H*C threads; out[dst] += h[src] * alpha
__global__ void scatter_k(const int* __restrict__ src, const int* __restrict__ dst,
                          const float* __restrict__ h, const float* __restrict__ w,
                          const float* __restrict__ denom, float* __restrict__ out,
                          int E, int Nn, int H, int C)
{
    int e = blockIdx.x;
    int t = threadIdx.x;                // 0..H*C-1
    int s, d;
    if (e < E) { s = src[e]; d = dst[e]; } else { s = e - E; d = s; }
    int head = t / C;
    float wgt = w[(size_t)e * H + head] / (denom[d * H + head] + 1e-16f);
    int HC = H * C;
    atomicAdd(&out[(size_t)d * HC + t], h[(size_t)s * HC + t] * wgt);
}

__global__ void bias_elu_k(float* __restrict__ x, const float* __restrict__ b, int n, int cmask)
{
    int i = blockIdx.x * blockDim.x + threadIdx.x;
    if (i < n) {
        float v = x[i] + b[i & cmask];
        x[i] = v > 0.f ? v : expm1f(v);
    }
}

// batch is sorted; per-block run-length accumulate then atomicAdd per graph run
__global__ void pool_k(const float* __restrict__ o2, const float* __restrict__ b2,
                       const int* __restrict__ batch, float* __restrict__ sums, int Nn, int C)
{
    int c = threadIdx.x;               // C = 128
    int n0 = blockIdx.x * 64;
    int n1 = min(n0 + 64, Nn);
    float local = 0.f;
    int gcur = batch[n0];
    float bc = b2[c];
    for (int n = n0; n < n1; ++n) {
        int g = batch[n];
        if (g != gcur) {
            atomicAdd(&sums[gcur * C + c], local);
            local = 0.f;
            gcur = g;
        }
        float v = o2[(size_t)n * C + c] + bc;
        local += v > 0.f ? v : expm1f(v);
    }
    atomicAdd(&sums[gcur * C + c], local);
}

// counts via binary search on sorted batch; then out = (sums/cnt) @ lin_w + lin_b
__global__ void final_k(const float* __restrict__ sums, const int* __restrict__ batch,
                        const float* __restrict__ lin_w, const float* __restrict__ lin_b,
                        float* __restrict__ out, int Nn, int G, int C, int NC)
{
    __shared__ float inv[64];
    int t = threadIdx.x;
    if (t < G) {
        int lo = 0, hi = Nn;
        while (lo < hi) { int mid = (lo + hi) >> 1; if (batch[mid] < t) lo = mid + 1; else hi = mid; }
        int lb = lo;
        lo = 0; hi = Nn;
        while (lo < hi) { int mid = (lo + hi) >> 1; if (batch[mid] < t + 1) lo = mid + 1; else hi = mid; }
        int cnt = lo - lb;
        inv[t] = 1.f / fmaxf((float)cnt, 1.f);
    }
    __syncthreads();
    if (t < G * NC) {
        int g = t / NC, k = t % NC;
        float acc = 0.f;
        for (int c = 0; c < C; ++c) acc += sums[g * C + c] * lin_w[c * NC + k];
        out[t] = acc * inv[g] + lin_b[k];
    }
}

extern "C" void kernel_launch(void* const* d_in, const int* in_sizes, int n_in,
                              void* d_out, int out_size, void* d_ws, size_t ws_size,
                              hipStream_t stream)
{
    const float* x      = (const float*)d_in[0];
    const int*   eidx   = (const int*)d_in[1];
    const int*   batch  = (const int*)d_in[2];
    const float* W1     = (const float*)d_in[3];
    const float* att_s1 = (const float*)d_in[4];
    const float* att_d1 = (const float*)d_in[5];
    const float* b1     = (const float*)d_in[6];
    const float* W2     = (const float*)d_in[7];
    const float* att_s2 = (const float*)d_in[8];
    const float* att_d2 = (const float*)d_in[9];
    const float* b2     = (const float*)d_in[10];
    const float* lin_w  = (const float*)d_in[11];
    const float* lin_b  = (const float*)d_in[12];

    const int Nn  = in_sizes[2];         // 50000
    const int E   = in_sizes[1] / 2;     // 800000
    const int FIN = in_sizes[0] / Nn;    // 128
    const int H1_ = 4, C1_ = 64, C2_ = 128, G = 32, NC = 5;
    const int D1 = H1_ * C1_;            // 256
    const int ET = E + Nn;               // edges + self loops

    const int* srcp = eidx;
    const int* dstp = eidx + E;

    float* ws = (float*)d_ws;
    size_t off = 0;
    auto alloc = [&](size_t n) { float* p = ws + off; off += n; return p; };
    float* h    = alloc((size_t)Nn * D1);   // h1, then h2 (first Nn*C2 of it)
    float* o1   = alloc((size_t)Nn * D1);   // out1 -> x2 (in place)
    float* o2   = alloc((size_t)Nn * C2_);
    float* aS1  = alloc((size_t)Nn * H1_);
    float* aD1  = alloc((size_t)Nn * H1_);
    float* mx1  = alloc((size_t)Nn * H1_);
    float* dn1  = alloc((size_t)Nn * H1_);
    float* aS2  = alloc(Nn);
    float* aD2  = alloc(Nn);
    float* mx2  = alloc(Nn);
    float* dn2  = alloc(Nn);
    float* wE   = alloc((size_t)ET * H1_);  // edge exp weights (layer2 reuses)
    float* sums = alloc((size_t)G * C2_);

    // ---------------- layer 1 ----------------
    dim3 g1((D1 + 63) / 64, (Nn + 63) / 64);
    gemm_tiled<64, 64, 16, 4, 4><<<g1, 256, 0, stream>>>(x, W1, h, Nn, D1, FIN);
    attn_scores<<<Nn * H1_, 64, 0, stream>>>(h, att_s1, att_d1, aS1, aD1, Nn, H1_, C1_);
    fill_f<<<(Nn * H1_ + 255) / 256, 256, 0, stream>>>(mx1, -1e30f, Nn * H1_);
    hipMemsetAsync(dn1, 0, (size_t)Nn * H1_ * 4, stream);
    hipMemsetAsync(o1, 0, (size_t)Nn * D1 * 4, stream);
    edge_max_k<<<(ET + 255) / 256, 256, 0, stream>>>(srcp, dstp, aS1, aD1, mx1, E, Nn, H1_);
    edge_exp_k<<<(ET + 255) / 256, 256, 0, stream>>>(srcp, dstp, aS1, aD1, mx1, wE, dn1, E, Nn, H1_);
    scatter_k<<<ET, D1, 0, stream>>>(srcp, dstp, h, wE, dn1, o1, E, Nn, H1_, C1_);
    bias_elu_k<<<((size_t)Nn * D1 + 255) / 256, 256, 0, stream>>>(o1, b1, Nn * D1, D1 - 1);

    // ---------------- layer 2 ----------------
    dim3 g2((C2_ + 63) / 64, (Nn + 63) / 64);
    gemm_tiled<64, 64, 16, 4, 4><<<g2, 256, 0, stream>>>(o1, W2, h, Nn, C2_, D1);
    attn_scores<<<Nn, 64, 0, stream>>>(h, att_s2, att_d2, aS2, aD2, Nn, 1, C2_);
    fill_f<<<(Nn + 255) / 256, 256, 0, stream>>>(mx2, -1e30f, Nn);
    hipMemsetAsync(dn2, 0, (size_t)Nn * 4, stream);
    hipMemsetAsync(o2, 0, (size_t)Nn * C2_ * 4, stream);
    edge_max_k<<<(ET + 255) / 256, 256, 0, stream>>>(srcp, dstp, aS2, aD2, mx2, E, Nn, 1);
    edge_exp_k<<<(ET + 255) / 256, 256, 0, stream>>>(srcp, dstp, aS2, aD2, mx2, wE, dn2, E, Nn, 1);
    scatter_k<<<ET, C2_, 0, stream>>>(srcp, dstp, h, wE, dn2, o2, E, Nn, 1, C2_);

    // ---------------- pool + classifier ----------------
    hipMemsetAsync(sums, 0, (size_t)G * C2_ * 4, stream);
    pool_k<<<(Nn + 63) / 64, C2_, 0, stream>>>(o2, b2, batch, sums, Nn, C2_);
    final_k<<<1, 256, 0, stream>>>(sums, batch, lin_w, lin_b, (float*)d_out, Nn, G, C2_, NC);
}

// Round 2
// 653.833 us; speedup vs baseline: 2.8373x; 2.8373x over previous
//
#include <hip/hip_runtime.h>
#include <math.h>

#define NEG_SLOPE 0.2f

__device__ inline float lrelu(float x) { return x > 0.f ? x : NEG_SLOPE * x; }

// ---------------- GEMM: C[M,N] = A[M,K] @ B[K,N], row-major, N%64==0, K%16==0 ----
template<int BM, int BN, int BK, int TM, int TN>
__global__ void gemm_tiled(const float* __restrict__ A, const float* __restrict__ B,
                           float* __restrict__ C, int M, int N, int K)
{
    __shared__ float As[BK][BM];
    __shared__ float Bs[BK][BN];
    const int tid = threadIdx.x;           // 256 threads
    const int tx = tid & 15, ty = tid >> 4;
    const int rowBase = blockIdx.y * BM;
    const int colBase = blockIdx.x * BN;

    float acc[TM][TN] = {};

    const int aRow = tid >> 2;             // 0..63
    const int aCol = (tid & 3) << 2;       // 0,4,8,12
    const int bRow = tid >> 4;             // 0..15
    const int bCol = (tid & 15) << 2;      // 0..60

    for (int k0 = 0; k0 < K; k0 += BK) {
        {
            int gr = rowBase + aRow;
            float4 v = make_float4(0.f, 0.f, 0.f, 0.f);
            if (gr < M) v = *(const float4*)(A + (size_t)gr * K + k0 + aCol);
            As[aCol + 0][aRow] = v.x;
            As[aCol + 1][aRow] = v.y;
            As[aCol + 2][aRow] = v.z;
            As[aCol + 3][aRow] = v.w;
        }
        {
            float4 v = *(const float4*)(B + (size_t)(k0 + bRow) * N + colBase + bCol);
            *(float4*)&Bs[bRow][bCol] = v;
        }
        __syncthreads();
#pragma unroll
        for (int k = 0; k < BK; ++k) {
            float ra[TM], rb[TN];
#pragma unroll
            for (int i = 0; i < TM; ++i) ra[i] = As[k][ty * TM + i];
#pragma unroll
            for (int j = 0; j < TN; ++j) rb[j] = Bs[k][tx * TN + j];
#pragma unroll
            for (int i = 0; i < TM; ++i)
#pragma unroll
                for (int j = 0; j < TN; ++j)
                    acc[i][j] += ra[i] * rb[j];
        }
        __syncthreads();
    }
#pragma unroll
    for (int i = 0; i < TM; ++i) {
        int gr = rowBase + ty * TM + i;
        if (gr >= M) continue;
        *(float4*)(C + (size_t)gr * N + colBase + tx * TN) =
            make_float4(acc[i][0], acc[i][1], acc[i][2], acc[i][3]);
    }
}

// ---- per-(node,head) attention logits: a_src/a_dst = sum_c h*att ---------------
__global__ void attn_scores(const float* __restrict__ h, const float* __restrict__ att_src,
                            const float* __restrict__ att_dst, float* __restrict__ a_src,
                            float* __restrict__ a_dst, int Nn, int H, int C)
{
    int b = blockIdx.x;            // n*H + head
    int n = b / H, hh = b % H;
    int lane = threadIdx.x;        // 64
    const float* hp = h + (size_t)n * H * C + (size_t)hh * C;
    const float* as = att_src + (size_t)hh * C;
    const float* ad = att_dst + (size_t)hh * C;
    float ss = 0.f, sd = 0.f;
    for (int c = lane; c < C; c += 64) {
        float v = hp[c];
        ss += v * as[c];
        sd += v * ad[c];
    }
#pragma unroll
    for (int off = 32; off > 0; off >>= 1) {
        ss += __shfl_down(ss, off);
        sd += __shfl_down(sd, off);
    }
    if (lane == 0) { a_src[b] = ss; a_dst[b] = sd; }
}

// =================== CSR build (dst-bucketed edge list) =========================
__global__ void count_k(const int* __restrict__ dst, int* __restrict__ counts, int E, int Nn)
{
    int e = blockIdx.x * blockDim.x + threadIdx.x;
    if (e >= E + Nn) return;
    int d = (e < E) ? dst[e] : (e - E);
    atomicAdd(&counts[d], 1);
}

// block-exclusive scan of 256 elements; emits per-element partial + block sum
__global__ void scan1_k(const int* __restrict__ counts, int* __restrict__ partial,
                        int* __restrict__ bsum, int Nn)
{
    __shared__ int sh[256];
    int i = blockIdx.x * 256 + threadIdx.x;
    int v = (i < Nn) ? counts[i] : 0;
    sh[threadIdx.x] = v;
    __syncthreads();
#pragma unroll
    for (int o = 1; o < 256; o <<= 1) {
        int t = (threadIdx.x >= o) ? sh[threadIdx.x - o] : 0;
        __syncthreads();
        sh[threadIdx.x] += t;
        __syncthreads();
    }
    if (i < Nn) partial[i] = sh[threadIdx.x] - v;   // exclusive
    if (threadIdx.x == 255) bsum[blockIdx.x] = sh[255];
}

__global__ void scan2_k(int* __restrict__ bsum, int nb)
{
    __shared__ int sh[256];
    int v = (threadIdx.x < nb) ? bsum[threadIdx.x] : 0;
    sh[threadIdx.x] = v;
    __syncthreads();
#pragma unroll
    for (int o = 1; o < 256; o <<= 1) {
        int t = (threadIdx.x >= o) ? sh[threadIdx.x - o] : 0;
        __syncthreads();
        sh[threadIdx.x] += t;
        __syncthreads();
    }
    if (threadIdx.x < nb) bsum[threadIdx.x] = sh[threadIdx.x] - v;  // exclusive
}

__global__ void scan3_k(const int* __restrict__ partial, const int* __restrict__ bsum,
                        int* __restrict__ rowptr, int* __restrict__ cursor, int Nn, int ET)
{
    int i = blockIdx.x * 256 + threadIdx.x;
    if (i < Nn) {
        int v = partial[i] + bsum[i >> 8];
        rowptr[i] = v;
        cursor[i] = v;
    }
    if (i == Nn) rowptr[Nn] = ET;
}

__global__ void build_k(const int* __restrict__ src, const int* __restrict__ dst,
                        int* __restrict__ cursor, int* __restrict__ esrc, int E, int Nn)
{
    int e = blockIdx.x * blockDim.x + threadIdx.x;
    if (e >= E + Nn) return;
    int s, d;
    if (e < E) { s = src[e]; d = dst[e]; } else { s = e - E; d = s; }
    int pos = atomicAdd(&cursor[d], 1);
    esrc[pos] = s;
}

// ========== per-dst softmax stats (max & denom), one wave per dst ===============
template<int H>
__global__ void stats_k(const int* __restrict__ rp, const int* __restrict__ esrc,
                        const float* __restrict__ aS, const float* __restrict__ aD,
                        float* __restrict__ mx, float* __restrict__ dn, int Nn)
{
    int d = blockIdx.x * (blockDim.x >> 6) + (threadIdx.x >> 6);
    int lane = threadIdx.x & 63;
    if (d >= Nn) return;
    int p0 = rp[d], p1 = rp[d + 1];
    float ad[H], m[H], sum[H];
#pragma unroll
    for (int h = 0; h < H; ++h) { ad[h] = aD[d * H + h]; m[h] = -1e30f; sum[h] = 0.f; }
    for (int p = p0 + lane; p < p1; p += 64) {
        int s = esrc[p];
#pragma unroll
        for (int h = 0; h < H; ++h)
            m[h] = fmaxf(m[h], lrelu(aS[s * H + h] + ad[h]));
    }
#pragma unroll
    for (int h = 0; h < H; ++h)
#pragma unroll
        for (int off = 32; off > 0; off >>= 1)
            m[h] = fmaxf(m[h], __shfl_xor(m[h], off));
    for (int p = p0 + lane; p < p1; p += 64) {
        int s = esrc[p];
#pragma unroll
        for (int h = 0; h < H; ++h)
            sum[h] += expf(lrelu(aS[s * H + h] + ad[h]) - m[h]);
    }
#pragma unroll
    for (int h = 0; h < H; ++h)
#pragma unroll
        for (int off = 32; off > 0; off >>= 1)
            sum[h] += __shfl_xor(sum[h], off);
    if (lane == 0) {
#pragma unroll
        for (int h = 0; h < H; ++h) { mx[d * H + h] = m[h]; dn[d * H + h] = sum[h]; }
    }
}

// ========== gather: out[d] = elu( sum_e w_e * h[src_e] + bias ) ================
// layer 1: H=4, C=64, 256 threads/block (one wave per head)
__global__ void gather1_k(const int* __restrict__ rp, const int* __restrict__ esrc,
                          const float* __restrict__ h, const float* __restrict__ aS,
                          const float* __restrict__ aD, const float* __restrict__ mx,
                          const float* __restrict__ dn, const float* __restrict__ bias,
                          float* __restrict__ out)
{
    int d = blockIdx.x;
    int t = threadIdx.x;              // 0..255
    int head = t >> 6;
    int p0 = rp[d], p1 = rp[d + 1];
    float adh = aD[d * 4 + head];
    float mh  = mx[d * 4 + head];
    float inv = 1.f / (dn[d * 4 + head] + 1e-16f);
    float acc = 0.f;
    int p = p0;
    for (; p + 1 < p1; p += 2) {
        int s0 = esrc[p], s1 = esrc[p + 1];
        float w0 = expf(lrelu(aS[s0 * 4 + head] + adh) - mh);
        float w1 = expf(lrelu(aS[s1 * 4 + head] + adh) - mh);
        float v0 = h[(size_t)s0 * 256 + t];
        float v1 = h[(size_t)s1 * 256 + t];
        acc += v0 * w0 + v1 * w1;
    }
    if (p < p1) {
        int s0 = esrc[p];
        float w0 = expf(lrelu(aS[s0 * 4 + head] + adh) - mh);
        acc += h[(size_t)s0 * 256 + t] * w0;
    }
    float v = acc * inv + bias[t];
    out[(size_t)d * 256 + t] = v > 0.f ? v : expm1f(v);
}

// layer 2: H=1, C=128, 128 threads/block (bias+elu deferred to pool)
__global__ void gather2_k(const int* __restrict__ rp, const int* __restrict__ esrc,
                          const float* __restrict__ h, const float* __restrict__ aS,
                          const float* __restrict__ aD, const float* __restrict__ mx,
                          const float* __restrict__ dn, float* __restrict__ out)
{
    int d = blockIdx.x;
    int t = threadIdx.x;              // 0..127
    int p0 = rp[d], p1 = rp[d + 1];
    float adh = aD[d];
    float mh  = mx[d];
    float inv = 1.f / (dn[d] + 1e-16f);
    float acc = 0.f;
    int p = p0;
    for (; p + 1 < p1; p += 2) {
        int s0 = esrc[p], s1 = esrc[p + 1];
        float w0 = expf(lrelu(aS[s0] + adh) - mh);
        float w1 = expf(lrelu(aS[s1] + adh) - mh);
        float v0 = h[(size_t)s0 * 128 + t];
        float v1 = h[(size_t)s1 * 128 + t];
        acc += v0 * w0 + v1 * w1;
    }
    if (p < p1) {
        int s0 = esrc[p];
        float w0 = expf(lrelu(aS[s0] + adh) - mh);
        acc += h[(size_t)s0 * 128 + t] * w0;
    }
    out[(size_t)d * 128 + t] = acc * inv;
}

// batch is sorted; per-block run-length accumulate then atomicAdd per graph run
__global__ void pool_k(const float* __restrict__ o2, const float* __restrict__ b2,
                       const int* __restrict__ batch, float* __restrict__ sums, int Nn, int C)
{
    int c = threadIdx.x;               // C = 128
    int n0 = blockIdx.x * 64;
    int n1 = min(n0 + 64, Nn);
    float local = 0.f;
    int gcur = batch[n0];
    float bc = b2[c];
    for (int n = n0; n < n1; ++n) {
        int g = batch[n];
        if (g != gcur) {
            atomicAdd(&sums[gcur * C + c], local);
            local = 0.f;
            gcur = g;
        }
        float v = o2[(size_t)n * C + c] + bc;
        local += v > 0.f ? v : expm1f(v);
    }
    atomicAdd(&sums[gcur * C + c], local);
}

// counts via binary search on sorted batch; then out = (sums/cnt) @ lin_w + lin_b
__global__ void final_k(const float* __restrict__ sums, const int* __restrict__ batch,
                        const float* __restrict__ lin_w, const float* __restrict__ lin_b,
                        float* __restrict__ out, int Nn, int G, int C, int NC)
{
    __shared__ float inv[64];
    int t = threadIdx.x;
    if (t < G) {
        int lo = 0, hi = Nn;
        while (lo < hi) { int mid = (lo + hi) >> 1; if (batch[mid] < t) lo = mid + 1; else hi = mid; }
        int lb = lo;
        lo = 0; hi = Nn;
        while (lo < hi) { int mid = (lo + hi) >> 1; if (batch[mid] < t + 1) lo = mid + 1; else hi = mid; }
        int cnt = lo - lb;
        inv[t] = 1.f / fmaxf((float)cnt, 1.f);
    }
    __syncthreads();
    if (t < G * NC) {
        int g = t / NC, k = t % NC;
        float acc = 0.f;
        for (int c = 0; c < C; ++c) acc += sums[g * C + c] * lin_w[c * NC + k];
        out[t] = acc * inv[g] + lin_b[k];
    }
}

extern "C" void kernel_launch(void* const* d_in, const int* in_sizes, int n_in,
                              void* d_out, int out_size, void* d_ws, size_t ws_size,
                              hipStream_t stream)
{
    const float* x      = (const float*)d_in[0];
    const int*   eidx   = (const int*)d_in[1];
    const int*   batch  = (const int*)d_in[2];
    const float* W1     = (const float*)d_in[3];
    const float* att_s1 = (const float*)d_in[4];
    const float* att_d1 = (const float*)d_in[5];
    const float* b1     = (const float*)d_in[6];
    const float* W2     = (const float*)d_in[7];
    const float* att_s2 = (const float*)d_in[8];
    const float* att_d2 = (const float*)d_in[9];
    const float* b2     = (const float*)d_in[10];
    const float* lin_w  = (const float*)d_in[11];
    const float* lin_b  = (const float*)d_in[12];

    const int Nn  = in_sizes[2];         // 50000
    const int E   = in_sizes[1] / 2;     // 800000
    const int FIN = in_sizes[0] / Nn;    // 128
    const int H1_ = 4, C1_ = 64, C2_ = 128, G = 32, NC = 5;
    const int D1 = H1_ * C1_;            // 256
    const int ET = E + Nn;               // edges + self loops

    const int* srcp = eidx;
    const int* dstp = eidx + E;

    float* ws = (float*)d_ws;
    size_t off = 0;
    auto alloc = [&](size_t n) { float* p = ws + off; off += n; return p; };
    float* h    = alloc((size_t)Nn * D1);   // h1; layer2 h2 occupies first Nn*C2
    float* o1   = alloc((size_t)Nn * D1);
    float* o2   = alloc((size_t)Nn * C2_);
    float* aS1  = alloc((size_t)Nn * H1_);
    float* aD1  = alloc((size_t)Nn * H1_);
    float* mx1  = alloc((size_t)Nn * H1_);
    float* dn1  = alloc((size_t)Nn * H1_);
    float* aS2  = alloc(Nn);
    float* aD2  = alloc(Nn);
    float* mx2  = alloc(Nn);
    float* dn2  = alloc(Nn);
    float* sums = alloc((size_t)G * C2_);
    int* iws    = (int*)(ws + off);
    int* counts = iws;                      // Nn   (also reused as cursor)
    int* partial= iws + Nn;                 // Nn
    int* rowptr = iws + 2 * Nn;             // Nn+1
    int* cursor = iws + 3 * Nn + 1;         // Nn
    int* bsum   = iws + 4 * Nn + 1;         // <=256
    int* esrc   = iws + 4 * Nn + 1 + 256;   // ET

    const int NB = (Nn + 255) / 256;

    // ---------------- CSR build (shared by both layers) ----------------
    hipMemsetAsync(counts, 0, (size_t)Nn * 4, stream);
    count_k<<<(ET + 255) / 256, 256, 0, stream>>>(dstp, counts, E, Nn);
    scan1_k<<<NB, 256, 0, stream>>>(counts, partial, bsum, Nn);
    scan2_k<<<1, 256, 0, stream>>>(bsum, NB);
    scan3_k<<<(Nn + 256) / 256, 256, 0, stream>>>(partial, bsum, rowptr, cursor, Nn, ET);
    build_k<<<(ET + 255) / 256, 256, 0, stream>>>(srcp, dstp, cursor, esrc, E, Nn);

    // ---------------- layer 1 ----------------
    dim3 g1((D1 + 63) / 64, (Nn + 63) / 64);
    gemm_tiled<64, 64, 16, 4, 4><<<g1, 256, 0, stream>>>(x, W1, h, Nn, D1, FIN);
    attn_scores<<<Nn * H1_, 64, 0, stream>>>(h, att_s1, att_d1, aS1, aD1, Nn, H1_, C1_);
    stats_k<4><<<(Nn + 3) / 4, 256, 0, stream>>>(rowptr, esrc, aS1, aD1, mx1, dn1, Nn);
    gather1_k<<<Nn, 256, 0, stream>>>(rowptr, esrc, h, aS1, aD1, mx1, dn1, b1, o1);

    // ---------------- layer 2 ----------------
    dim3 g2((C2_ + 63) / 64, (Nn + 63) / 64);
    gemm_tiled<64, 64, 16, 4, 4><<<g2, 256, 0, stream>>>(o1, W2, h, Nn, C2_, D1);
    attn_scores<<<Nn, 64, 0, stream>>>(h, att_s2, att_d2, aS2, aD2, Nn, 1, C2_);
    stats_k<1><<<(Nn + 3) / 4, 256, 0, stream>>>(rowptr, esrc, aS2, aD2, mx2, dn2, Nn);
    gather2_k<<<Nn, 128, 0, stream>>>(rowptr, esrc, h, aS2, aD2, mx2, dn2, o2);

    // ---------------- pool + classifier ----------------
    hipMemsetAsync(sums, 0, (size_t)G * C2_ * 4, stream);
    pool_k<<<(Nn + 63) / 64, C2_, 0, stream>>>(o2, b2, batch, sums, Nn, C2_);
    final_k<<<1, 256, 0, stream>>>(sums, batch, lin_w, lin_b, (float*)d_out, Nn, G, C2_, NC);
}

// Round 4
// 639.570 us; speedup vs baseline: 2.9005x; 1.0223x over previous
//
#include <hip/hip_runtime.h>
#include <math.h>

#define NEG_SLOPE 0.2f

__device__ inline float lrelu(float x) { return x > 0.f ? x : NEG_SLOPE * x; }

// ---------------- GEMM: C[M,N] = A[M,K] @ B[K,N], row-major, N%64==0, K%16==0 ----
template<int BM, int BN, int BK, int TM, int TN>
__global__ void gemm_tiled(const float* __restrict__ A, const float* __restrict__ B,
                           float* __restrict__ C, int M, int N, int K)
{
    __shared__ float As[BK][BM];
    __shared__ float Bs[BK][BN];
    const int tid = threadIdx.x;           // 256 threads
    const int tx = tid & 15, ty = tid >> 4;
    const int rowBase = blockIdx.y * BM;
    const int colBase = blockIdx.x * BN;

    float acc[TM][TN] = {};

    const int aRow = tid >> 2;             // 0..63
    const int aCol = (tid & 3) << 2;       // 0,4,8,12
    const int bRow = tid >> 4;             // 0..15
    const int bCol = (tid & 15) << 2;      // 0..60

    for (int k0 = 0; k0 < K; k0 += BK) {
        {
            int gr = rowBase + aRow;
            float4 v = make_float4(0.f, 0.f, 0.f, 0.f);
            if (gr < M) v = *(const float4*)(A + (size_t)gr * K + k0 + aCol);
            As[aCol + 0][aRow] = v.x;
            As[aCol + 1][aRow] = v.y;
            As[aCol + 2][aRow] = v.z;
            As[aCol + 3][aRow] = v.w;
        }
        {
            float4 v = *(const float4*)(B + (size_t)(k0 + bRow) * N + colBase + bCol);
            *(float4*)&Bs[bRow][bCol] = v;
        }
        __syncthreads();
#pragma unroll
        for (int k = 0; k < BK; ++k) {
            float ra[TM], rb[TN];
#pragma unroll
            for (int i = 0; i < TM; ++i) ra[i] = As[k][ty * TM + i];
#pragma unroll
            for (int j = 0; j < TN; ++j) rb[j] = Bs[k][tx * TN + j];
#pragma unroll
            for (int i = 0; i < TM; ++i)
#pragma unroll
                for (int j = 0; j < TN; ++j)
                    acc[i][j] += ra[i] * rb[j];
        }
        __syncthreads();
    }
#pragma unroll
    for (int i = 0; i < TM; ++i) {
        int gr = rowBase + ty * TM + i;
        if (gr >= M) continue;
        *(float4*)(C + (size_t)gr * N + colBase + tx * TN) =
            make_float4(acc[i][0], acc[i][1], acc[i][2], acc[i][3]);
    }
}

// ---- per-(node,head) attention logits: a_src/a_dst = sum_c h*att ---------------
__global__ void attn_scores(const float* __restrict__ h, const float* __restrict__ att_src,
                            const float* __restrict__ att_dst, float* __restrict__ a_src,
                            float* __restrict__ a_dst, int Nn, int H, int C)
{
    int b = blockIdx.x;            // n*H + head
    int n = b / H, hh = b % H;
    int lane = threadIdx.x;        // 64
    const float* hp = h + (size_t)n * H * C + (size_t)hh * C;
    const float* as = att_src + (size_t)hh * C;
    const float* ad = att_dst + (size_t)hh * C;
    float ss = 0.f, sd = 0.f;
    for (int c = lane; c < C; c += 64) {
        float v = hp[c];
        ss += v * as[c];
        sd += v * ad[c];
    }
#pragma unroll
    for (int off = 32; off > 0; off >>= 1) {
        ss += __shfl_down(ss, off);
        sd += __shfl_down(sd, off);
    }
    if (lane == 0) { a_src[b] = ss; a_dst[b] = sd; }
}

// =================== CSR build (dst-bucketed edge list) =========================
__global__ void count_k(const int* __restrict__ dst, int* __restrict__ counts, int E, int Nn)
{
    int e = blockIdx.x * blockDim.x + threadIdx.x;
    if (e >= E + Nn) return;
    int d = (e < E) ? dst[e] : (e - E);
    atomicAdd(&counts[d], 1);
}

__global__ void scan1_k(const int* __restrict__ counts, int* __restrict__ partial,
                        int* __restrict__ bsum, int Nn)
{
    __shared__ int sh[256];
    int i = blockIdx.x * 256 + threadIdx.x;
    int v = (i < Nn) ? counts[i] : 0;
    sh[threadIdx.x] = v;
    __syncthreads();
#pragma unroll
    for (int o = 1; o < 256; o <<= 1) {
        int t = (threadIdx.x >= o) ? sh[threadIdx.x - o] : 0;
        __syncthreads();
        sh[threadIdx.x] += t;
        __syncthreads();
    }
    if (i < Nn) partial[i] = sh[threadIdx.x] - v;   // exclusive
    if (threadIdx.x == 255) bsum[blockIdx.x] = sh[255];
}

__global__ void scan2_k(int* __restrict__ bsum, int nb)
{
    __shared__ int sh[256];
    int v = (threadIdx.x < nb) ? bsum[threadIdx.x] : 0;
    sh[threadIdx.x] = v;
    __syncthreads();
#pragma unroll
    for (int o = 1; o < 256; o <<= 1) {
        int t = (threadIdx.x >= o) ? sh[threadIdx.x - o] : 0;
        __syncthreads();
        sh[threadIdx.x] += t;
        __syncthreads();
    }
    if (threadIdx.x < nb) bsum[threadIdx.x] = sh[threadIdx.x] - v;  // exclusive
}

__global__ void scan3_k(const int* __restrict__ partial, const int* __restrict__ bsum,
                        int* __restrict__ rowptr, int* __restrict__ cursor, int Nn, int ET)
{
    int i = blockIdx.x * 256 + threadIdx.x;
    if (i < Nn) {
        int v = partial[i] + bsum[i >> 8];
        rowptr[i] = v;
        cursor[i] = v;
    }
    if (i == Nn) rowptr[Nn] = ET;
}

__global__ void build_k(const int* __restrict__ src, const int* __restrict__ dst,
                        int* __restrict__ cursor, int* __restrict__ esrc, int E, int Nn)
{
    int e = blockIdx.x * blockDim.x + threadIdx.x;
    if (e >= E + Nn) return;
    int s, d;
    if (e < E) { s = src[e]; d = dst[e]; } else { s = e - E; d = s; }
    int pos = atomicAdd(&cursor[d], 1);
    esrc[pos] = s;
}

// ==== per-dst softmax: max, denom, then write NORMALIZED edge weights ==========
// H=4: aS layout [N,4] -> float4 loads; wE layout [ET,4] coalesced writes.
__global__ void stats4_k(const int* __restrict__ rp, const int* __restrict__ esrc,
                         const float* __restrict__ aS, const float* __restrict__ aD,
                         float* __restrict__ wE, int Nn)
{
    int d = blockIdx.x * (blockDim.x >> 6) + (threadIdx.x >> 6);
    int lane = threadIdx.x & 63;
    if (d >= Nn) return;
    int p0 = rp[d], p1 = rp[d + 1];
    float4 ad = *(const float4*)&aD[d * 4];
    float m0 = -1e30f, m1 = -1e30f, m2 = -1e30f, m3 = -1e30f;
    for (int p = p0 + lane; p < p1; p += 64) {
        int s = esrc[p];
        float4 a = *(const float4*)&aS[s * 4];
        m0 = fmaxf(m0, lrelu(a.x + ad.x));
        m1 = fmaxf(m1, lrelu(a.y + ad.y));
        m2 = fmaxf(m2, lrelu(a.z + ad.z));
        m3 = fmaxf(m3, lrelu(a.w + ad.w));
    }
#pragma unroll
    for (int off = 32; off > 0; off >>= 1) {
        m0 = fmaxf(m0, __shfl_xor(m0, off));
        m1 = fmaxf(m1, __shfl_xor(m1, off));
        m2 = fmaxf(m2, __shfl_xor(m2, off));
        m3 = fmaxf(m3, __shfl_xor(m3, off));
    }
    float s0 = 0.f, s1 = 0.f, s2 = 0.f, s3 = 0.f;
    for (int p = p0 + lane; p < p1; p += 64) {
        int s = esrc[p];
        float4 a = *(const float4*)&aS[s * 4];
        s0 += expf(lrelu(a.x + ad.x) - m0);
        s1 += expf(lrelu(a.y + ad.y) - m1);
        s2 += expf(lrelu(a.z + ad.z) - m2);
        s3 += expf(lrelu(a.w + ad.w) - m3);
    }
#pragma unroll
    for (int off = 32; off > 0; off >>= 1) {
        s0 += __shfl_xor(s0, off);
        s1 += __shfl_xor(s1, off);
        s2 += __shfl_xor(s2, off);
        s3 += __shfl_xor(s3, off);
    }
    float i0 = 1.f / (s0 + 1e-16f), i1 = 1.f / (s1 + 1e-16f);
    float i2 = 1.f / (s2 + 1e-16f), i3 = 1.f / (s3 + 1e-16f);
    for (int p = p0 + lane; p < p1; p += 64) {
        int s = esrc[p];
        float4 a = *(const float4*)&aS[s * 4];
        float4 w;
        w.x = expf(lrelu(a.x + ad.x) - m0) * i0;
        w.y = expf(lrelu(a.y + ad.y) - m1) * i1;
        w.z = expf(lrelu(a.z + ad.z) - m2) * i2;
        w.w = expf(lrelu(a.w + ad.w) - m3) * i3;
        *(float4*)&wE[(size_t)p * 4] = w;
    }
}

// H=1
__global__ void stats1_k(const int* __restrict__ rp, const int* __restrict__ esrc,
                         const float* __restrict__ aS, const float* __restrict__ aD,
                         float* __restrict__ wE, int Nn)
{
    int d = blockIdx.x * (blockDim.x >> 6) + (threadIdx.x >> 6);
    int lane = threadIdx.x & 63;
    if (d >= Nn) return;
    int p0 = rp[d], p1 = rp[d + 1];
    float ad = aD[d];
    float m = -1e30f;
    for (int p = p0 + lane; p < p1; p += 64) {
        int s = esrc[p];
        m = fmaxf(m, lrelu(aS[s] + ad));
    }
#pragma unroll
    for (int off = 32; off > 0; off >>= 1) m = fmaxf(m, __shfl_xor(m, off));
    float sum = 0.f;
    for (int p = p0 + lane; p < p1; p += 64) {
        int s = esrc[p];
        sum += expf(lrelu(aS[s] + ad) - m);
    }
#pragma unroll
    for (int off = 32; off > 0; off >>= 1) sum += __shfl_xor(sum, off);
    float inv = 1.f / (sum + 1e-16f);
    for (int p = p0 + lane; p < p1; p += 64) {
        int s = esrc[p];
        wE[p] = expf(lrelu(aS[s] + ad) - m) * inv;
    }
}

// ===== gather layer 1: out[d] = elu( sum_e w_e * h[src_e] + bias ), C=256 ======
// one wave per dst, lane owns 4 channels (float4)
__global__ void gather1_k(const int* __restrict__ rp, const int* __restrict__ esrc,
                          const float* __restrict__ h, const float* __restrict__ wE,
                          const float* __restrict__ bias, float* __restrict__ out, int Nn)
{
    int d = blockIdx.x * 4 + (threadIdx.x >> 6);
    int lane = threadIdx.x & 63;
    if (d >= Nn) return;
    int c4 = lane << 2;               // channel base 0..252
    int head = lane >> 4;             // c4 >> 6
    int p0 = rp[d], p1 = rp[d + 1];
    float ax = 0.f, ay = 0.f, az = 0.f, aw = 0.f;
    int p = p0;
    for (; p + 1 < p1; p += 2) {
        int s0 = esrc[p], s1 = esrc[p + 1];
        float w0 = wE[(size_t)p * 4 + head];
        float w1 = wE[(size_t)(p + 1) * 4 + head];
        float4 v0 = *(const float4*)&h[(size_t)s0 * 256 + c4];
        float4 v1 = *(const float4*)&h[(size_t)s1 * 256 + c4];
        ax += v0.x * w0 + v1.x * w1;
        ay += v0.y * w0 + v1.y * w1;
        az += v0.z * w0 + v1.z * w1;
        aw += v0.w * w0 + v1.w * w1;
    }
    if (p < p1) {
        int s0 = esrc[p];
        float w0 = wE[(size_t)p * 4 + head];
        float4 v0 = *(const float4*)&h[(size_t)s0 * 256 + c4];
        ax += v0.x * w0; ay += v0.y * w0; az += v0.z * w0; aw += v0.w * w0;
    }
    float4 b4 = *(const float4*)&bias[c4];
    float4 r;
    r.x = ax + b4.x; r.x = r.x > 0.f ? r.x : expm1f(r.x);
    r.y = ay + b4.y; r.y = r.y > 0.f ? r.y : expm1f(r.y);
    r.z = az + b4.z; r.z = r.z > 0.f ? r.z : expm1f(r.z);
    r.w = aw + b4.w; r.w = r.w > 0.f ? r.w : expm1f(r.w);
    *(float4*)&out[(size_t)d * 256 + c4] = r;
}

// ===== gather layer 2: C=128, one wave per dst, half-waves take alternate edges
__global__ void gather2_k(const int* __restrict__ rp, const int* __restrict__ esrc,
                          const float* __restrict__ h, const float* __restrict__ wE,
                          float* __restrict__ out, int Nn)
{
    int d = blockIdx.x * 4 + (threadIdx.x >> 6);
    int lane = threadIdx.x & 63;
    if (d >= Nn) return;
    int half = lane >> 5;             // 0 or 1
    int c4 = (lane & 31) << 2;        // 0..124
    int p0 = rp[d], p1 = rp[d + 1];
    float ax = 0.f, ay = 0.f, az = 0.f, aw = 0.f;
    for (int p = p0 + half; p < p1; p += 2) {
        int s = esrc[p];
        float w = wE[p];
        float4 v = *(const float4*)&h[(size_t)s * 128 + c4];
        ax += v.x * w; ay += v.y * w; az += v.z * w; aw += v.w * w;
    }
    ax += __shfl_xor(ax, 32);
    ay += __shfl_xor(ay, 32);
    az += __shfl_xor(az, 32);
    aw += __shfl_xor(aw, 32);
    if (half == 0)
        *(float4*)&out[(size_t)d * 128 + c4] = make_float4(ax, ay, az, aw);
}

// batch is sorted; per-block run-length accumulate then atomicAdd per graph run
__global__ void pool_k(const float* __restrict__ o2, const float* __restrict__ b2,
                       const int* __restrict__ batch, float* __restrict__ sums, int Nn, int C)
{
    int c = threadIdx.x;               // C = 128
    int n0 = blockIdx.x * 64;
    int n1 = min(n0 + 64, Nn);
    float local = 0.f;
    int gcur = batch[n0];
    float bc = b2[c];
    for (int n = n0; n < n1; ++n) {
        int g = batch[n];
        if (g != gcur) {
            atomicAdd(&sums[gcur * C + c], local);
            local = 0.f;
            gcur = g;
        }
        float v = o2[(size_t)n * C + c] + bc;
        local += v > 0.f ? v : expm1f(v);
    }
    atomicAdd(&sums[gcur * C + c], local);
}

// counts via binary search on sorted batch; then out = (sums/cnt) @ lin_w + lin_b
__global__ void final_k(const float* __restrict__ sums, const int* __restrict__ batch,
                        const float* __restrict__ lin_w, const float* __restrict__ lin_b,
                        float* __restrict__ out, int Nn, int G, int C, int NC)
{
    __shared__ float inv[64];
    int t = threadIdx.x;
    if (t < G) {
        int lo = 0, hi = Nn;
        while (lo < hi) { int mid = (lo + hi) >> 1; if (batch[mid] < t) lo = mid + 1; else hi = mid; }
        int lb = lo;
        lo = 0; hi = Nn;
        while (lo < hi) { int mid = (lo + hi) >> 1; if (batch[mid] < t + 1) lo = mid + 1; else hi = mid; }
        int cnt = lo - lb;
        inv[t] = 1.f / fmaxf((float)cnt, 1.f);
    }
    __syncthreads();
    if (t < G * NC) {
        int g = t / NC, k = t % NC;
        float acc = 0.f;
        for (int c = 0; c < C; ++c) acc += sums[g * C + c] * lin_w[c * NC + k];
        out[t] = acc * inv[g] + lin_b[k];
    }
}

extern "C" void kernel_launch(void* const* d_in, const int* in_sizes, int n_in,
                              void* d_out, int out_size, void* d_ws, size_t ws_size,
                              hipStream_t stream)
{
    const float* x      = (const float*)d_in[0];
    const int*   eidx   = (const int*)d_in[1];
    const int*   batch  = (const int*)d_in[2];
    const float* W1     = (const float*)d_in[3];
    const float* att_s1 = (const float*)d_in[4];
    const float* att_d1 = (const float*)d_in[5];
    const float* b1     = (const float*)d_in[6];
    const float* W2     = (const float*)d_in[7];
    const float* att_s2 = (const float*)d_in[8];
    const float* att_d2 = (const float*)d_in[9];
    const float* b2     = (const float*)d_in[10];
    const float* lin_w  = (const float*)d_in[11];
    const float* lin_b  = (const float*)d_in[12];

    const int Nn  = in_sizes[2];         // 50000
    const int E   = in_sizes[1] / 2;     // 800000
    const int FIN = in_sizes[0] / Nn;    // 128
    const int H1_ = 4, C1_ = 64, C2_ = 128, G = 32, NC = 5;
    const int D1 = H1_ * C1_;            // 256
    const int ET = E + Nn;               // edges + self loops

    const int* srcp = eidx;
    const int* dstp = eidx + E;

    float* ws = (float*)d_ws;
    size_t off = 0;
    auto alloc = [&](size_t n) { float* p = ws + off; off += n; return p; };
    float* h    = alloc((size_t)Nn * D1);   // h1; layer2 h2 occupies first Nn*C2
    float* o1   = alloc((size_t)Nn * D1);
    float* o2   = alloc((size_t)Nn * C2_);
    float* aS1  = alloc((size_t)Nn * H1_);
    float* aD1  = alloc((size_t)Nn * H1_);
    float* aS2  = alloc(Nn);
    float* aD2  = alloc(Nn);
    float* wE   = alloc((size_t)ET * H1_);  // normalized edge weights (L1); L2 reuses first ET
    float* sums = alloc((size_t)G * C2_);
    int* iws    = (int*)(ws + off);
    int* counts = iws;                      // Nn
    int* partial= iws + Nn;                 // Nn
    int* rowptr = iws + 2 * Nn;             // Nn+1
    int* cursor = iws + 3 * Nn + 1;         // Nn
    int* bsum   = iws + 4 * Nn + 1;         // <=256
    int* esrc   = iws + 4 * Nn + 1 + 256;   // ET

    const int NB = (Nn + 255) / 256;

    // ---------------- CSR build (shared by both layers) ----------------
    hipMemsetAsync(counts, 0, (size_t)Nn * 4, stream);
    count_k<<<(ET + 255) / 256, 256, 0, stream>>>(dstp, counts, E, Nn);
    scan1_k<<<NB, 256, 0, stream>>>(counts, partial, bsum, Nn);
    scan2_k<<<1, 256, 0, stream>>>(bsum, NB);
    scan3_k<<<(Nn + 256) / 256, 256, 0, stream>>>(partial, bsum, rowptr, cursor, Nn, ET);
    build_k<<<(ET + 255) / 256, 256, 0, stream>>>(srcp, dstp, cursor, esrc, E, Nn);

    // ---------------- layer 1 ----------------
    dim3 g1((D1 + 63) / 64, (Nn + 63) / 64);
    gemm_tiled<64, 64, 16, 4, 4><<<g1, 256, 0, stream>>>(x, W1, h, Nn, D1, FIN);
    attn_scores<<<Nn * H1_, 64, 0, stream>>>(h, att_s1, att_d1, aS1, aD1, Nn, H1_, C1_);
    stats4_k<<<(Nn + 3) / 4, 256, 0, stream>>>(rowptr, esrc, aS1, aD1, wE, Nn);
    gather1_k<<<(Nn + 3) / 4, 256, 0, stream>>>(rowptr, esrc, h, wE, b1, o1, Nn);

    // ---------------- layer 2 ----------------
    dim3 g2((C2_ + 63) / 64, (Nn + 63) / 64);
    gemm_tiled<64, 64, 16, 4, 4><<<g2, 256, 0, stream>>>(o1, W2, h, Nn, C2_, D1);
    attn_scores<<<Nn, 64, 0, stream>>>(h, att_s2, att_d2, aS2, aD2, Nn, 1, C2_);
    stats1_k<<<(Nn + 3) / 4, 256, 0, stream>>>(rowptr, esrc, aS2, aD2, wE, Nn);
    gather2_k<<<(Nn + 3) / 4, 256, 0, stream>>>(rowptr, esrc, h, wE, o2, Nn);

    // ---------------- pool + classifier ----------------
    hipMemsetAsync(sums, 0, (size_t)G * C2_ * 4, stream);
    pool_k<<<(Nn + 63) / 64, C2_, 0, stream>>>(o2, b2, batch, sums, Nn, C2_);
    final_k<<<1, 256, 0, stream>>>(sums, batch, lin_w, lin_b, (float*)d_out, Nn, G, C2_, NC);
}

// Round 6
// 580.022 us; speedup vs baseline: 3.1983x; 1.1027x over previous
//
#include <hip/hip_runtime.h>
#include <math.h>

#define NEG_SLOPE 0.2f

__device__ inline float lrelu(float x) { return x > 0.f ? x : NEG_SLOPE * x; }

// ---------------- bf16 split helpers (RNE) ----------------
__device__ inline unsigned short f2bf(float f) {
    unsigned u = __float_as_uint(f);
    unsigned r = (u + 0x7fffu + ((u >> 16) & 1u)) >> 16;
    return (unsigned short)r;
}
__device__ inline float bf2f(unsigned short h) {
    return __uint_as_float(((unsigned)h) << 16);
}

typedef __attribute__((ext_vector_type(8))) short s16x8;
typedef __attribute__((ext_vector_type(4))) float f32x4;

// Split W [K,N] fp32 into BT [N, 2K] bf16 (transposed, hi in k<K, lo in k>=K)
__global__ void convW_k(const float* __restrict__ W, unsigned short* __restrict__ BT,
                        int K, int N)
{
    int i = blockIdx.x * blockDim.x + threadIdx.x;
    if (i >= N * K) return;
    int n = i / K, k = i - n * K;
    float f = W[(size_t)k * N + n];
    unsigned short hi = f2bf(f);
    unsigned short lo = f2bf(f - bf2f(hi));
    BT[(size_t)n * (2 * K) + k] = hi;
    BT[(size_t)n * (2 * K) + K + k] = lo;
}

// ---- MFMA GEMM: C[M,N] = A[M,K] @ W[K,N] via bf16 hi/lo split (K'=2K) --------
// A fp32 row-major, BT = pre-split [N][2K] bf16. BM=64, BK=32, 256 threads.
template<int N, int K>
__launch_bounds__(256)
__global__ void gemm_mfma(const float* __restrict__ A, const unsigned short* __restrict__ BT,
                          float* __restrict__ C, int M)
{
    constexpr int ITERS = (2 * K) / 32;
    constexpr int WN = N / 4;          // columns per wave
    constexpr int NT = WN / 16;        // 16-wide tiles per wave
    constexpr int NCH = (N * 4) / 256; // 8-short chunks per thread for B staging
    __shared__ unsigned short As[64 * 40] __attribute__((aligned(16)));
    __shared__ unsigned short Bs[N * 40] __attribute__((aligned(16)));
    const int t = threadIdx.x;
    const int wave = t >> 6, lane = t & 63;
    const int quad = lane >> 4, l15 = lane & 15;
    const int rowBase = blockIdx.x * 64;

    f32x4 acc[4][NT];
#pragma unroll
    for (int mi = 0; mi < 4; ++mi)
#pragma unroll
        for (int ni = 0; ni < NT; ++ni)
            acc[mi][ni] = (f32x4){0.f, 0.f, 0.f, 0.f};

    const int ar = t >> 2;             // A-stage row 0..63
    const int ak = (t & 3) << 3;       // A-stage k seg 0,8,16,24
    const int bc = (t * NCH) >> 2;     // B-stage column
    const int bks = (t * NCH) & 3;     // B-stage starting chunk

    for (int it = 0; it < ITERS; ++it) {
        const int kb = (it % (K / 32)) * 32;
        const bool lophase = (it * 32) >= K;
        // ---- stage A (fp32 -> bf16 hi or lo)
        {
            int gr = rowBase + ar;
            float f[8] = {0.f, 0.f, 0.f, 0.f, 0.f, 0.f, 0.f, 0.f};
            if (gr < M) {
                const float* ap = A + (size_t)gr * K + kb + ak;
                float4 v0 = *(const float4*)ap;
                float4 v1 = *(const float4*)(ap + 4);
                f[0] = v0.x; f[1] = v0.y; f[2] = v0.z; f[3] = v0.w;
                f[4] = v1.x; f[5] = v1.y; f[6] = v1.z; f[7] = v1.w;
            }
            s16x8 av;
#pragma unroll
            for (int j = 0; j < 8; ++j) {
                unsigned short hi = f2bf(f[j]);
                unsigned short o = lophase ? f2bf(f[j] - bf2f(hi)) : hi;
                av[j] = (short)o;
            }
            *(s16x8*)&As[ar * 40 + ak] = av;
        }
        // ---- stage B (pre-split bf16, contiguous copy)
        {
            const unsigned short* bp = BT + (size_t)bc * (2 * K) + it * 32 + bks * 8;
            unsigned short* dp = &Bs[bc * 40 + bks * 8];
#pragma unroll
            for (int j = 0; j < NCH; ++j)
                *(s16x8*)(dp + j * 8) = *(const s16x8*)(bp + j * 8);
        }
        __syncthreads();
        // ---- compute: 4 x NT tiles of 16x16, one mfma covers K=32
        s16x8 af[4], bfr[NT];
#pragma unroll
        for (int mi = 0; mi < 4; ++mi)
            af[mi] = *(const s16x8*)&As[(mi * 16 + l15) * 40 + quad * 8];
#pragma unroll
        for (int ni = 0; ni < NT; ++ni)
            bfr[ni] = *(const s16x8*)&Bs[(wave * WN + ni * 16 + l15) * 40 + quad * 8];
#pragma unroll
        for (int mi = 0; mi < 4; ++mi)
#pragma unroll
            for (int ni = 0; ni < NT; ++ni)
                acc[mi][ni] = __builtin_amdgcn_mfma_f32_16x16x32_bf16(
                    af[mi], bfr[ni], acc[mi][ni], 0, 0, 0);
        __syncthreads();
    }
    // ---- epilogue: D layout col=lane&15, row=quad*4+reg
#pragma unroll
    for (int mi = 0; mi < 4; ++mi) {
        int row = rowBase + mi * 16 + quad * 4;
#pragma unroll
        for (int r = 0; r < 4; ++r) {
            if (row + r < M) {
#pragma unroll
                for (int ni = 0; ni < NT; ++ni)
                    C[(size_t)(row + r) * N + wave * WN + ni * 16 + l15] = acc[mi][ni][r];
            }
        }
    }
}

// ---- per-(node,head) attention logits: a_src/a_dst = sum_c h*att ---------------
__global__ void attn_scores(const float* __restrict__ h, const float* __restrict__ att_src,
                            const float* __restrict__ att_dst, float* __restrict__ a_src,
                            float* __restrict__ a_dst, int Nn, int H, int C)
{
    int b = blockIdx.x;            // n*H + head
    int n = b / H, hh = b % H;
    int lane = threadIdx.x;        // 64
    const float* hp = h + (size_t)n * H * C + (size_t)hh * C;
    const float* as = att_src + (size_t)hh * C;
    const float* ad = att_dst + (size_t)hh * C;
    float ss = 0.f, sd = 0.f;
    for (int c = lane; c < C; c += 64) {
        float v = hp[c];
        ss += v * as[c];
        sd += v * ad[c];
    }
#pragma unroll
    for (int off = 32; off > 0; off >>= 1) {
        ss += __shfl_down(ss, off);
        sd += __shfl_down(sd, off);
    }
    if (lane == 0) { a_src[b] = ss; a_dst[b] = sd; }
}

// =================== CSR build (dst-bucketed edge list) =========================
__global__ void count_k(const int* __restrict__ dst, int* __restrict__ counts, int E, int Nn)
{
    int e = blockIdx.x * blockDim.x + threadIdx.x;
    if (e >= E + Nn) return;
    int d = (e < E) ? dst[e] : (e - E);
    atomicAdd(&counts[d], 1);
}

__global__ void scan1_k(const int* __restrict__ counts, int* __restrict__ partial,
                        int* __restrict__ bsum, int Nn)
{
    __shared__ int sh[256];
    int i = blockIdx.x * 256 + threadIdx.x;
    int v = (i < Nn) ? counts[i] : 0;
    sh[threadIdx.x] = v;
    __syncthreads();
#pragma unroll
    for (int o = 1; o < 256; o <<= 1) {
        int t = (threadIdx.x >= o) ? sh[threadIdx.x - o] : 0;
        __syncthreads();
        sh[threadIdx.x] += t;
        __syncthreads();
    }
    if (i < Nn) partial[i] = sh[threadIdx.x] - v;   // exclusive
    if (threadIdx.x == 255) bsum[blockIdx.x] = sh[255];
}

__global__ void scan2_k(int* __restrict__ bsum, int nb)
{
    __shared__ int sh[256];
    int v = (threadIdx.x < nb) ? bsum[threadIdx.x] : 0;
    sh[threadIdx.x] = v;
    __syncthreads();
#pragma unroll
    for (int o = 1; o < 256; o <<= 1) {
        int t = (threadIdx.x >= o) ? sh[threadIdx.x - o] : 0;
        __syncthreads();
        sh[threadIdx.x] += t;
        __syncthreads();
    }
    if (threadIdx.x < nb) bsum[threadIdx.x] = sh[threadIdx.x] - v;  // exclusive
}

__global__ void scan3_k(const int* __restrict__ partial, const int* __restrict__ bsum,
                        int* __restrict__ rowptr, int* __restrict__ cursor, int Nn, int ET)
{
    int i = blockIdx.x * 256 + threadIdx.x;
    if (i < Nn) {
        int v = partial[i] + bsum[i >> 8];
        rowptr[i] = v;
        cursor[i] = v;
    }
    if (i == Nn) rowptr[Nn] = ET;
}

__global__ void build_k(const int* __restrict__ src, const int* __restrict__ dst,
                        int* __restrict__ cursor, int* __restrict__ esrc, int E, int Nn)
{
    int e = blockIdx.x * blockDim.x + threadIdx.x;
    if (e >= E + Nn) return;
    int s, d;
    if (e < E) { s = src[e]; d = dst[e]; } else { s = e - E; d = s; }
    int pos = atomicAdd(&cursor[d], 1);
    esrc[pos] = s;
}

// ==== per-dst softmax, 3 passes caching logits/exp in wE ========================
// H=4: aS layout [N,4]; wE layout [ET,4].
__global__ void stats4_k(const int* __restrict__ rp, const int* __restrict__ esrc,
                         const float* __restrict__ aS, const float* __restrict__ aD,
                         float* __restrict__ wE, int Nn)
{
    int d = blockIdx.x * (blockDim.x >> 6) + (threadIdx.x >> 6);
    int lane = threadIdx.x & 63;
    if (d >= Nn) return;
    int p0 = rp[d], p1 = rp[d + 1];
    float4 ad = *(const float4*)&aD[d * 4];
    float m0 = -1e30f, m1 = -1e30f, m2 = -1e30f, m3 = -1e30f;
    for (int p = p0 + lane; p < p1; p += 64) {          // pass 1: logits -> wE, max
        int s = esrc[p];
        float4 a = *(const float4*)&aS[s * 4];
        float4 l;
        l.x = lrelu(a.x + ad.x); l.y = lrelu(a.y + ad.y);
        l.z = lrelu(a.z + ad.z); l.w = lrelu(a.w + ad.w);
        *(float4*)&wE[(size_t)p * 4] = l;
        m0 = fmaxf(m0, l.x); m1 = fmaxf(m1, l.y);
        m2 = fmaxf(m2, l.z); m3 = fmaxf(m3, l.w);
    }
#pragma unroll
    for (int off = 32; off > 0; off >>= 1) {
        m0 = fmaxf(m0, __shfl_xor(m0, off));
        m1 = fmaxf(m1, __shfl_xor(m1, off));
        m2 = fmaxf(m2, __shfl_xor(m2, off));
        m3 = fmaxf(m3, __shfl_xor(m3, off));
    }
    float s0 = 0.f, s1 = 0.f, s2 = 0.f, s3 = 0.f;
    for (int p = p0 + lane; p < p1; p += 64) {          // pass 2: exp -> wE, sum
        float4 l = *(const float4*)&wE[(size_t)p * 4];
        float4 e;
        e.x = expf(l.x - m0); e.y = expf(l.y - m1);
        e.z = expf(l.z - m2); e.w = expf(l.w - m3);
        *(float4*)&wE[(size_t)p * 4] = e;
        s0 += e.x; s1 += e.y; s2 += e.z; s3 += e.w;
    }
#pragma unroll
    for (int off = 32; off > 0; off >>= 1) {
        s0 += __shfl_xor(s0, off);
        s1 += __shfl_xor(s1, off);
        s2 += __shfl_xor(s2, off);
        s3 += __shfl_xor(s3, off);
    }
    float i0 = 1.f / (s0 + 1e-16f), i1 = 1.f / (s1 + 1e-16f);
    float i2 = 1.f / (s2 + 1e-16f), i3 = 1.f / (s3 + 1e-16f);
    for (int p = p0 + lane; p < p1; p += 64) {          // pass 3: normalize
        float4 e = *(const float4*)&wE[(size_t)p * 4];
        e.x *= i0; e.y *= i1; e.z *= i2; e.w *= i3;
        *(float4*)&wE[(size_t)p * 4] = e;
    }
}

// H=1
__global__ void stats1_k(const int* __restrict__ rp, const int* __restrict__ esrc,
                         const float* __restrict__ aS, const float* __restrict__ aD,
                         float* __restrict__ wE, int Nn)
{
    int d = blockIdx.x * (blockDim.x >> 6) + (threadIdx.x >> 6);
    int lane = threadIdx.x & 63;
    if (d >= Nn) return;
    int p0 = rp[d], p1 = rp[d + 1];
    float ad = aD[d];
    float m = -1e30f;
    for (int p = p0 + lane; p < p1; p += 64) {
        int s = esrc[p];
        float l = lrelu(aS[s] + ad);
        wE[p] = l;
        m = fmaxf(m, l);
    }
#pragma unroll
    for (int off = 32; off > 0; off >>= 1) m = fmaxf(m, __shfl_xor(m, off));
    float sum = 0.f;
    for (int p = p0 + lane; p < p1; p += 64) {
        float e = expf(wE[p] - m);
        wE[p] = e;
        sum += e;
    }
#pragma unroll
    for (int off = 32; off > 0; off >>= 1) sum += __shfl_xor(sum, off);
    float inv = 1.f / (sum + 1e-16f);
    for (int p = p0 + lane; p < p1; p += 64)
        wE[p] *= inv;
}

// ===== gather layer 1: out[d] = elu( sum_e w_e * h[src_e] + bias ), C=256 ======
// one wave per dst, lane owns 4 channels; unroll 4 edges for MLP
__global__ void gather1_k(const int* __restrict__ rp, const int* __restrict__ esrc,
                          const float* __restrict__ h, const float* __restrict__ wE,
                          const float* __restrict__ bias, float* __restrict__ out, int Nn)
{
    int d = blockIdx.x * 4 + (threadIdx.x >> 6);
    int lane = threadIdx.x & 63;
    if (d >= Nn) return;
    int c4 = lane << 2;               // channel base 0..252
    int head = lane >> 4;
    int p0 = rp[d], p1 = rp[d + 1];
    float ax = 0.f, ay = 0.f, az = 0.f, aw = 0.f;
    int p = p0;
    for (; p + 4 <= p1; p += 4) {
        int s0 = esrc[p], s1 = esrc[p + 1], s2 = esrc[p + 2], s3 = esrc[p + 3];
        float w0 = wE[(size_t)p * 4 + head];
        float w1 = wE[(size_t)(p + 1) * 4 + head];
        float w2 = wE[(size_t)(p + 2) * 4 + head];
        float w3 = wE[(size_t)(p + 3) * 4 + head];
        float4 v0 = *(const float4*)&h[(size_t)s0 * 256 + c4];
        float4 v1 = *(const float4*)&h[(size_t)s1 * 256 + c4];
        float4 v2 = *(const float4*)&h[(size_t)s2 * 256 + c4];
        float4 v3 = *(const float4*)&h[(size_t)s3 * 256 + c4];
        ax += v0.x * w0 + v1.x * w1 + v2.x * w2 + v3.x * w3;
        ay += v0.y * w0 + v1.y * w1 + v2.y * w2 + v3.y * w3;
        az += v0.z * w0 + v1.z * w1 + v2.z * w2 + v3.z * w3;
        aw += v0.w * w0 + v1.w * w1 + v2.w * w2 + v3.w * w3;
    }
    for (; p < p1; ++p) {
        int s0 = esrc[p];
        float w0 = wE[(size_t)p * 4 + head];
        float4 v0 = *(const float4*)&h[(size_t)s0 * 256 + c4];
        ax += v0.x * w0; ay += v0.y * w0; az += v0.z * w0; aw += v0.w * w0;
    }
    float4 b4 = *(const float4*)&bias[c4];
    float4 r;
    r.x = ax + b4.x; r.x = r.x > 0.f ? r.x : expm1f(r.x);
    r.y = ay + b4.y; r.y = r.y > 0.f ? r.y : expm1f(r.y);
    r.z = az + b4.z; r.z = r.z > 0.f ? r.z : expm1f(r.z);
    r.w = aw + b4.w; r.w = r.w > 0.f ? r.w : expm1f(r.w);
    *(float4*)&out[(size_t)d * 256 + c4] = r;
}

// ===== gather layer 2: C=128, half-waves take alternate edges, unroll 2 ========
__global__ void gather2_k(const int* __restrict__ rp, const int* __restrict__ esrc,
                          const float* __restrict__ h, const float* __restrict__ wE,
                          float* __restrict__ out, int Nn)
{
    int d = blockIdx.x * 4 + (threadIdx.x >> 6);
    int lane = threadIdx.x & 63;
    if (d >= Nn) return;
    int half = lane >> 5;             // 0 or 1
    int c4 = (lane & 31) << 2;        // 0..124
    int p0 = rp[d], p1 = rp[d + 1];
    float ax = 0.f, ay = 0.f, az = 0.f, aw = 0.f;
    int p = p0 + half;
    for (; p + 2 < p1; p += 4) {
        int s0 = esrc[p], s1 = esrc[p + 2];
        float w0 = wE[p], w1 = wE[p + 2];
        float4 v0 = *(const float4*)&h[(size_t)s0 * 128 + c4];
        float4 v1 = *(const float4*)&h[(size_t)s1 * 128 + c4];
        ax += v0.x * w0 + v1.x * w1;
        ay += v0.y * w0 + v1.y * w1;
        az += v0.z * w0 + v1.z * w1;
        aw += v0.w * w0 + v1.w * w1;
    }
    for (; p < p1; p += 2) {
        int s = esrc[p];
        float w = wE[p];
        float4 v = *(const float4*)&h[(size_t)s * 128 + c4];
        ax += v.x * w; ay += v.y * w; az += v.z * w; aw += v.w * w;
    }
    ax += __shfl_xor(ax, 32);
    ay += __shfl_xor(ay, 32);
    az += __shfl_xor(az, 32);
    aw += __shfl_xor(aw, 32);
    if (half == 0)
        *(float4*)&out[(size_t)d * 128 + c4] = make_float4(ax, ay, az, aw);
}

// batch is sorted; per-block run-length accumulate then atomicAdd per graph run
__global__ void pool_k(const float* __restrict__ o2, const float* __restrict__ b2,
                       const int* __restrict__ batch, float* __restrict__ sums, int Nn, int C)
{
    int c = threadIdx.x;               // C = 128
    int n0 = blockIdx.x * 64;
    int n1 = min(n0 + 64, Nn);
    float local = 0.f;
    int gcur = batch[n0];
    float bc = b2[c];
    for (int n = n0; n < n1; ++n) {
        int g = batch[n];
        if (g != gcur) {
            atomicAdd(&sums[gcur * C + c], local);
            local = 0.f;
            gcur = g;
        }
        float v = o2[(size_t)n * C + c] + bc;
        local += v > 0.f ? v : expm1f(v);
    }
    atomicAdd(&sums[gcur * C + c], local);
}

// counts via binary search on sorted batch; then out = (sums/cnt) @ lin_w + lin_b
__global__ void final_k(const float* __restrict__ sums, const int* __restrict__ batch,
                        const float* __restrict__ lin_w, const float* __restrict__ lin_b,
                        float* __restrict__ out, int Nn, int G, int C, int NC)
{
    __shared__ float inv[64];
    int t = threadIdx.x;
    if (t < G) {
        int lo = 0, hi = Nn;
        while (lo < hi) { int mid = (lo + hi) >> 1; if (batch[mid] < t) lo = mid + 1; else hi = mid; }
        int lb = lo;
        lo = 0; hi = Nn;
        while (lo < hi) { int mid = (lo + hi) >> 1; if (batch[mid] < t + 1) lo = mid + 1; else hi = mid; }
        int cnt = lo - lb;
        inv[t] = 1.f / fmaxf((float)cnt, 1.f);
    }
    __syncthreads();
    if (t < G * NC) {
        int g = t / NC, k = t % NC;
        float acc = 0.f;
        for (int c = 0; c < C; ++c) acc += sums[g * C + c] * lin_w[c * NC + k];
        out[t] = acc * inv[g] + lin_b[k];
    }
}

extern "C" void kernel_launch(void* const* d_in, const int* in_sizes, int n_in,
                              void* d_out, int out_size, void* d_ws, size_t ws_size,
                              hipStream_t stream)
{
    const float* x      = (const float*)d_in[0];
    const int*   eidx   = (const int*)d_in[1];
    const int*   batch  = (const int*)d_in[2];
    const float* W1     = (const float*)d_in[3];
    const float* att_s1 = (const float*)d_in[4];
    const float* att_d1 = (const float*)d_in[5];
    const float* b1     = (const float*)d_in[6];
    const float* W2     = (const float*)d_in[7];
    const float* att_s2 = (const float*)d_in[8];
    const float* att_d2 = (const float*)d_in[9];
    const float* b2     = (const float*)d_in[10];
    const float* lin_w  = (const float*)d_in[11];
    const float* lin_b  = (const float*)d_in[12];

    const int Nn  = in_sizes[2];         // 50000
    const int E   = in_sizes[1] / 2;     // 800000
    const int H1_ = 4, C1_ = 64, C2_ = 128, G = 32, NC = 5;
    const int D1 = H1_ * C1_;            // 256
    const int ET = E + Nn;               // edges + self loops
    const int K1 = 128, K2 = 256;

    const int* srcp = eidx;
    const int* dstp = eidx + E;

    float* ws = (float*)d_ws;
    size_t off = 0;
    auto alloc = [&](size_t n) { float* p = ws + off; off += n; return p; };
    float* h    = alloc((size_t)Nn * D1);   // h1; layer2 h2 occupies first Nn*C2
    float* o1   = alloc((size_t)Nn * D1);
    float* o2   = alloc((size_t)Nn * C2_);
    float* aS1  = alloc((size_t)Nn * H1_);
    float* aD1  = alloc((size_t)Nn * H1_);
    float* aS2  = alloc(Nn);
    float* aD2  = alloc(Nn);
    float* wE   = alloc((size_t)ET * H1_);  // normalized edge weights (L1); L2 reuses first ET
    float* sums = alloc((size_t)G * C2_);
    unsigned short* BT1 = (unsigned short*)alloc(D1 * K1);        // 256 x 256 bf16 = 32768 floats
    unsigned short* BT2 = (unsigned short*)alloc(C2_ * K2);       // 128 x 512 bf16 = 32768 floats
    int* iws    = (int*)(ws + off);
    int* counts = iws;                      // Nn
    int* partial= iws + Nn;                 // Nn
    int* rowptr = iws + 2 * Nn;             // Nn+1
    int* cursor = iws + 3 * Nn + 1;         // Nn
    int* bsum   = iws + 4 * Nn + 1;         // <=256
    int* esrc   = iws + 4 * Nn + 1 + 256;   // ET

    const int NB = (Nn + 255) / 256;
    const int GB = (Nn + 63) / 64;          // gemm blocks (BM=64)

    // ---------------- CSR build (shared by both layers) ----------------
    hipMemsetAsync(counts, 0, (size_t)Nn * 4, stream);
    count_k<<<(ET + 255) / 256, 256, 0, stream>>>(dstp, counts, E, Nn);
    scan1_k<<<NB, 256, 0, stream>>>(counts, partial, bsum, Nn);
    scan2_k<<<1, 256, 0, stream>>>(bsum, NB);
    scan3_k<<<(Nn + 256) / 256, 256, 0, stream>>>(partial, bsum, rowptr, cursor, Nn, ET);
    build_k<<<(ET + 255) / 256, 256, 0, stream>>>(srcp, dstp, cursor, esrc, E, Nn);

    // ---------------- weight split (bf16 hi/lo, transposed) ----------------
    convW_k<<<(D1 * K1 + 255) / 256, 256, 0, stream>>>(W1, BT1, K1, D1);
    convW_k<<<(C2_ * K2 + 255) / 256, 256, 0, stream>>>(W2, BT2, K2, C2_);

    // ---------------- layer 1 ----------------
    gemm_mfma<256, 128><<<GB, 256, 0, stream>>>(x, BT1, h, Nn);
    attn_scores<<<Nn * H1_, 64, 0, stream>>>(h, att_s1, att_d1, aS1, aD1, Nn, H1_, C1_);
    stats4_k<<<(Nn + 3) / 4, 256, 0, stream>>>(rowptr, esrc, aS1, aD1, wE, Nn);
    gather1_k<<<(Nn + 3) / 4, 256, 0, stream>>>(rowptr, esrc, h, wE, b1, o1, Nn);

    // ---------------- layer 2 ----------------
    gemm_mfma<128, 256><<<GB, 256, 0, stream>>>(o1, BT2, h, Nn);
    attn_scores<<<Nn, 64, 0, stream>>>(h, att_s2, att_d2, aS2, aD2, Nn, 1, C2_);
    stats1_k<<<(Nn + 3) / 4, 256, 0, stream>>>(rowptr, esrc, aS2, aD2, wE, Nn);
    gather2_k<<<(Nn + 3) / 4, 256, 0, stream>>>(rowptr, esrc, h, wE, o2, Nn);

    // ---------------- pool + classifier ----------------
    hipMemsetAsync(sums, 0, (size_t)G * C2_ * 4, stream);
    pool_k<<<GB, C2_, 0, stream>>>(o2, b2, batch, sums, Nn, C2_);
    final_k<<<1, 256, 0, stream>>>(sums, batch, lin_w, lin_b, (float*)d_out, Nn, G, C2_, NC);
}

// Round 7
// 538.747 us; speedup vs baseline: 3.4433x; 1.0766x over previous
//
#include <hip/hip_runtime.h>
#include <math.h>

#define NEG_SLOPE 0.2f

__device__ inline float lrelu(float x) { return x > 0.f ? x : NEG_SLOPE * x; }

// ---------------- bf16 split helpers (RNE) ----------------
__device__ inline unsigned short f2bf(float f) {
    unsigned u = __float_as_uint(f);
    unsigned r = (u + 0x7fffu + ((u >> 16) & 1u)) >> 16;
    return (unsigned short)r;
}
__device__ inline float bf2f(unsigned short h) {
    return __uint_as_float(((unsigned)h) << 16);
}

typedef __attribute__((ext_vector_type(8))) short s16x8;
typedef __attribute__((ext_vector_type(4))) float f32x4;

// Split W [K,N] fp32 into BT [N, 2K] bf16 (transposed, hi in k<K, lo in k>=K)
__global__ void convW_k(const float* __restrict__ W, unsigned short* __restrict__ BT,
                        int K, int N)
{
    int i = blockIdx.x * blockDim.x + threadIdx.x;
    if (i >= N * K) return;
    int n = i / K, k = i - n * K;
    float f = W[(size_t)k * N + n];
    unsigned short hi = f2bf(f);
    unsigned short lo = f2bf(f - bf2f(hi));
    BT[(size_t)n * (2 * K) + k] = hi;
    BT[(size_t)n * (2 * K) + K + k] = lo;
}

// ---- MFMA GEMM: C[M,N] = A[M,K] @ W[K,N] via bf16 hi/lo split (K'=2K) --------
// A fp32 row-major, BT = pre-split [N][2K] bf16. BM=64, BK=32, 256 threads.
template<int N, int K>
__launch_bounds__(256)
__global__ void gemm_mfma(const float* __restrict__ A, const unsigned short* __restrict__ BT,
                          float* __restrict__ C, int M)
{
    constexpr int ITERS = (2 * K) / 32;
    constexpr int WN = N / 4;          // columns per wave
    constexpr int NT = WN / 16;        // 16-wide tiles per wave
    constexpr int NCH = (N * 4) / 256; // 8-short chunks per thread for B staging
    __shared__ unsigned short As[64 * 40] __attribute__((aligned(16)));
    __shared__ unsigned short Bs[N * 40] __attribute__((aligned(16)));
    const int t = threadIdx.x;
    const int wave = t >> 6, lane = t & 63;
    const int quad = lane >> 4, l15 = lane & 15;
    const int rowBase = blockIdx.x * 64;

    f32x4 acc[4][NT];
#pragma unroll
    for (int mi = 0; mi < 4; ++mi)
#pragma unroll
        for (int ni = 0; ni < NT; ++ni)
            acc[mi][ni] = (f32x4){0.f, 0.f, 0.f, 0.f};

    const int ar = t >> 2;             // A-stage row 0..63
    const int ak = (t & 3) << 3;       // A-stage k seg 0,8,16,24
    const int bc = (t * NCH) >> 2;     // B-stage column
    const int bks = (t * NCH) & 3;     // B-stage starting chunk

    for (int it = 0; it < ITERS; ++it) {
        const int kb = (it % (K / 32)) * 32;
        const bool lophase = (it * 32) >= K;
        // ---- stage A (fp32 -> bf16 hi or lo)
        {
            int gr = rowBase + ar;
            float f[8] = {0.f, 0.f, 0.f, 0.f, 0.f, 0.f, 0.f, 0.f};
            if (gr < M) {
                const float* ap = A + (size_t)gr * K + kb + ak;
                float4 v0 = *(const float4*)ap;
                float4 v1 = *(const float4*)(ap + 4);
                f[0] = v0.x; f[1] = v0.y; f[2] = v0.z; f[3] = v0.w;
                f[4] = v1.x; f[5] = v1.y; f[6] = v1.z; f[7] = v1.w;
            }
            s16x8 av;
#pragma unroll
            for (int j = 0; j < 8; ++j) {
                unsigned short hi = f2bf(f[j]);
                unsigned short o = lophase ? f2bf(f[j] - bf2f(hi)) : hi;
                av[j] = (short)o;
            }
            *(s16x8*)&As[ar * 40 + ak] = av;
        }
        // ---- stage B (pre-split bf16, contiguous copy)
        {
            const unsigned short* bp = BT + (size_t)bc * (2 * K) + it * 32 + bks * 8;
            unsigned short* dp = &Bs[bc * 40 + bks * 8];
#pragma unroll
            for (int j = 0; j < NCH; ++j)
                *(s16x8*)(dp + j * 8) = *(const s16x8*)(bp + j * 8);
        }
        __syncthreads();
        // ---- compute: 4 x NT tiles of 16x16, one mfma covers K=32
        s16x8 af[4], bfr[NT];
#pragma unroll
        for (int mi = 0; mi < 4; ++mi)
            af[mi] = *(const s16x8*)&As[(mi * 16 + l15) * 40 + quad * 8];
#pragma unroll
        for (int ni = 0; ni < NT; ++ni)
            bfr[ni] = *(const s16x8*)&Bs[(wave * WN + ni * 16 + l15) * 40 + quad * 8];
#pragma unroll
        for (int mi = 0; mi < 4; ++mi)
#pragma unroll
            for (int ni = 0; ni < NT; ++ni)
                acc[mi][ni] = __builtin_amdgcn_mfma_f32_16x16x32_bf16(
                    af[mi], bfr[ni], acc[mi][ni], 0, 0, 0);
        __syncthreads();
    }
    // ---- epilogue: D layout col=lane&15, row=quad*4+reg
#pragma unroll
    for (int mi = 0; mi < 4; ++mi) {
        int row = rowBase + mi * 16 + quad * 4;
#pragma unroll
        for (int r = 0; r < 4; ++r) {
            if (row + r < M) {
#pragma unroll
                for (int ni = 0; ni < NT; ++ni)
                    C[(size_t)(row + r) * N + wave * WN + ni * 16 + l15] = acc[mi][ni][r];
            }
        }
    }
}

// ---- per-(node,head) attention logits: a_src/a_dst = sum_c h*att ---------------
__global__ void attn_scores(const float* __restrict__ h, const float* __restrict__ att_src,
                            const float* __restrict__ att_dst, float* __restrict__ a_src,
                            float* __restrict__ a_dst, int Nn, int H, int C)
{
    int b = blockIdx.x;            // n*H + head
    int n = b / H, hh = b % H;
    int lane = threadIdx.x;        // 64
    const float* hp = h + (size_t)n * H * C + (size_t)hh * C;
    const float* as = att_src + (size_t)hh * C;
    const float* ad = att_dst + (size_t)hh * C;
    float ss = 0.f, sd = 0.f;
    for (int c = lane; c < C; c += 64) {
        float v = hp[c];
        ss += v * as[c];
        sd += v * ad[c];
    }
#pragma unroll
    for (int off = 32; off > 0; off >>= 1) {
        ss += __shfl_down(ss, off);
        sd += __shfl_down(sd, off);
    }
    if (lane == 0) { a_src[b] = ss; a_dst[b] = sd; }
}

// =================== CSR build (dst-bucketed edge list) =========================
__global__ void count_k(const int* __restrict__ dst, int* __restrict__ counts, int E, int Nn)
{
    int e = blockIdx.x * blockDim.x + threadIdx.x;
    if (e >= E + Nn) return;
    int d = (e < E) ? dst[e] : (e - E);
    atomicAdd(&counts[d], 1);
}

__global__ void scan1_k(const int* __restrict__ counts, int* __restrict__ partial,
                        int* __restrict__ bsum, int Nn)
{
    __shared__ int sh[256];
    int i = blockIdx.x * 256 + threadIdx.x;
    int v = (i < Nn) ? counts[i] : 0;
    sh[threadIdx.x] = v;
    __syncthreads();
#pragma unroll
    for (int o = 1; o < 256; o <<= 1) {
        int t = (threadIdx.x >= o) ? sh[threadIdx.x - o] : 0;
        __syncthreads();
        sh[threadIdx.x] += t;
        __syncthreads();
    }
    if (i < Nn) partial[i] = sh[threadIdx.x] - v;   // exclusive
    if (threadIdx.x == 255) bsum[blockIdx.x] = sh[255];
}

__global__ void scan2_k(int* __restrict__ bsum, int nb)
{
    __shared__ int sh[256];
    int v = (threadIdx.x < nb) ? bsum[threadIdx.x] : 0;
    sh[threadIdx.x] = v;
    __syncthreads();
#pragma unroll
    for (int o = 1; o < 256; o <<= 1) {
        int t = (threadIdx.x >= o) ? sh[threadIdx.x - o] : 0;
        __syncthreads();
        sh[threadIdx.x] += t;
        __syncthreads();
    }
    if (threadIdx.x < nb) bsum[threadIdx.x] = sh[threadIdx.x] - v;  // exclusive
}

__global__ void scan3_k(const int* __restrict__ partial, const int* __restrict__ bsum,
                        int* __restrict__ rowptr, int* __restrict__ cursor, int Nn, int ET)
{
    int i = blockIdx.x * 256 + threadIdx.x;
    if (i < Nn) {
        int v = partial[i] + bsum[i >> 8];
        rowptr[i] = v;
        cursor[i] = v;
    }
    if (i == Nn) rowptr[Nn] = ET;
}

__global__ void build_k(const int* __restrict__ src, const int* __restrict__ dst,
                        int* __restrict__ cursor, int* __restrict__ esrc, int E, int Nn)
{
    int e = blockIdx.x * blockDim.x + threadIdx.x;
    if (e >= E + Nn) return;
    int s, d;
    if (e < E) { s = src[e]; d = dst[e]; } else { s = e - E; d = s; }
    int pos = atomicAdd(&cursor[d], 1);
    esrc[pos] = s;
}

// ===== gather layer 1 with ONLINE softmax: out[d]=elu(Σ e^l·h[src]/(den+eps)+b)
// one wave per dst, lane owns 4 channels; H=4, C=64, head = lane>>4
__global__ void gather1_k(const int* __restrict__ rp, const int* __restrict__ esrc,
                          const float* __restrict__ h, const float* __restrict__ aS,
                          const float* __restrict__ aD, const float* __restrict__ bias,
                          float* __restrict__ out, int Nn)
{
    int d = blockIdx.x * 4 + (threadIdx.x >> 6);
    int lane = threadIdx.x & 63;
    if (d >= Nn) return;
    int c4 = lane << 2;               // channel base 0..252
    int head = lane >> 4;
    int p0 = rp[d], p1 = rp[d + 1];
    float adh = aD[d * 4 + head];
    const float* aSh = aS + head;
    float m = -1e30f, den = 0.f;
    float ax = 0.f, ay = 0.f, az = 0.f, aw = 0.f;
    int p = p0;
    for (; p + 4 <= p1; p += 4) {
        int s0 = esrc[p], s1 = esrc[p + 1], s2 = esrc[p + 2], s3 = esrc[p + 3];
        float l0 = lrelu(aSh[s0 * 4] + adh);
        float l1 = lrelu(aSh[s1 * 4] + adh);
        float l2 = lrelu(aSh[s2 * 4] + adh);
        float l3 = lrelu(aSh[s3 * 4] + adh);
        float lm = fmaxf(fmaxf(l0, l1), fmaxf(l2, l3));
        if (lm > m) {
            float r = __expf(m - lm);
            ax *= r; ay *= r; az *= r; aw *= r; den *= r;
            m = lm;
        }
        float w0 = __expf(l0 - m), w1 = __expf(l1 - m);
        float w2 = __expf(l2 - m), w3 = __expf(l3 - m);
        den += w0 + w1 + w2 + w3;
        float4 v0 = *(const float4*)&h[(size_t)s0 * 256 + c4];
        float4 v1 = *(const float4*)&h[(size_t)s1 * 256 + c4];
        float4 v2 = *(const float4*)&h[(size_t)s2 * 256 + c4];
        float4 v3 = *(const float4*)&h[(size_t)s3 * 256 + c4];
        ax += v0.x * w0 + v1.x * w1 + v2.x * w2 + v3.x * w3;
        ay += v0.y * w0 + v1.y * w1 + v2.y * w2 + v3.y * w3;
        az += v0.z * w0 + v1.z * w1 + v2.z * w2 + v3.z * w3;
        aw += v0.w * w0 + v1.w * w1 + v2.w * w2 + v3.w * w3;
    }
    for (; p < p1; ++p) {
        int s0 = esrc[p];
        float l0 = lrelu(aSh[s0 * 4] + adh);
        if (l0 > m) {
            float r = __expf(m - l0);
            ax *= r; ay *= r; az *= r; aw *= r; den *= r;
            m = l0;
        }
        float w0 = __expf(l0 - m);
        den += w0;
        float4 v0 = *(const float4*)&h[(size_t)s0 * 256 + c4];
        ax += v0.x * w0; ay += v0.y * w0; az += v0.z * w0; aw += v0.w * w0;
    }
    float inv = 1.f / (den + 1e-16f);
    float4 b4 = *(const float4*)&bias[c4];
    float4 r;
    r.x = ax * inv + b4.x; r.x = r.x > 0.f ? r.x : expm1f(r.x);
    r.y = ay * inv + b4.y; r.y = r.y > 0.f ? r.y : expm1f(r.y);
    r.z = az * inv + b4.z; r.z = r.z > 0.f ? r.z : expm1f(r.z);
    r.w = aw * inv + b4.w; r.w = r.w > 0.f ? r.w : expm1f(r.w);
    *(float4*)&out[(size_t)d * 256 + c4] = r;
}

// ===== gather layer 2, online softmax: C=128, half-waves take alternate edges ==
__global__ void gather2_k(const int* __restrict__ rp, const int* __restrict__ esrc,
                          const float* __restrict__ h, const float* __restrict__ aS,
                          const float* __restrict__ aD, float* __restrict__ out, int Nn)
{
    int d = blockIdx.x * 4 + (threadIdx.x >> 6);
    int lane = threadIdx.x & 63;
    if (d >= Nn) return;
    int half = lane >> 5;             // 0 or 1
    int c4 = (lane & 31) << 2;        // 0..124
    int p0 = rp[d], p1 = rp[d + 1];
    float adh = aD[d];
    float m = -1e30f, den = 0.f;
    float ax = 0.f, ay = 0.f, az = 0.f, aw = 0.f;
    int p = p0 + half;
    for (; p + 2 < p1; p += 4) {
        int s0 = esrc[p], s1 = esrc[p + 2];
        float l0 = lrelu(aS[s0] + adh);
        float l1 = lrelu(aS[s1] + adh);
        float lm = fmaxf(l0, l1);
        if (lm > m) {
            float r = __expf(m - lm);
            ax *= r; ay *= r; az *= r; aw *= r; den *= r;
            m = lm;
        }
        float w0 = __expf(l0 - m), w1 = __expf(l1 - m);
        den += w0 + w1;
        float4 v0 = *(const float4*)&h[(size_t)s0 * 128 + c4];
        float4 v1 = *(const float4*)&h[(size_t)s1 * 128 + c4];
        ax += v0.x * w0 + v1.x * w1;
        ay += v0.y * w0 + v1.y * w1;
        az += v0.z * w0 + v1.z * w1;
        aw += v0.w * w0 + v1.w * w1;
    }
    for (; p < p1; p += 2) {
        int s0 = esrc[p];
        float l0 = lrelu(aS[s0] + adh);
        if (l0 > m) {
            float r = __expf(m - l0);
            ax *= r; ay *= r; az *= r; aw *= r; den *= r;
            m = l0;
        }
        float w0 = __expf(l0 - m);
        den += w0;
        float4 v0 = *(const float4*)&h[(size_t)s0 * 128 + c4];
        ax += v0.x * w0; ay += v0.y * w0; az += v0.z * w0; aw += v0.w * w0;
    }
    // merge the two halves (both lanes compute identical mm, rescale, then sum)
    float mo = __shfl_xor(m, 32);
    float mm = fmaxf(m, mo);
    float fsc = __expf(m - mm);
    ax *= fsc; ay *= fsc; az *= fsc; aw *= fsc; den *= fsc;
    ax += __shfl_xor(ax, 32);
    ay += __shfl_xor(ay, 32);
    az += __shfl_xor(az, 32);
    aw += __shfl_xor(aw, 32);
    den += __shfl_xor(den, 32);
    float inv = 1.f / (den + 1e-16f);
    if (half == 0)
        *(float4*)&out[(size_t)d * 128 + c4] =
            make_float4(ax * inv, ay * inv, az * inv, aw * inv);
}

// batch is sorted; per-block run-length accumulate then atomicAdd per graph run
__global__ void pool_k(const float* __restrict__ o2, const float* __restrict__ b2,
                       const int* __restrict__ batch, float* __restrict__ sums, int Nn, int C)
{
    int c = threadIdx.x;               // C = 128
    int n0 = blockIdx.x * 64;
    int n1 = min(n0 + 64, Nn);
    float local = 0.f;
    int gcur = batch[n0];
    float bc = b2[c];
    for (int n = n0; n < n1; ++n) {
        int g = batch[n];
        if (g != gcur) {
            atomicAdd(&sums[gcur * C + c], local);
            local = 0.f;
            gcur = g;
        }
        float v = o2[(size_t)n * C + c] + bc;
        local += v > 0.f ? v : expm1f(v);
    }
    atomicAdd(&sums[gcur * C + c], local);
}

// counts via binary search on sorted batch; then out = (sums/cnt) @ lin_w + lin_b
__global__ void final_k(const float* __restrict__ sums, const int* __restrict__ batch,
                        const float* __restrict__ lin_w, const float* __restrict__ lin_b,
                        float* __restrict__ out, int Nn, int G, int C, int NC)
{
    __shared__ float inv[64];
    int t = threadIdx.x;
    if (t < G) {
        int lo = 0, hi = Nn;
        while (lo < hi) { int mid = (lo + hi) >> 1; if (batch[mid] < t) lo = mid + 1; else hi = mid; }
        int lb = lo;
        lo = 0; hi = Nn;
        while (lo < hi) { int mid = (lo + hi) >> 1; if (batch[mid] < t + 1) lo = mid + 1; else hi = mid; }
        int cnt = lo - lb;
        inv[t] = 1.f / fmaxf((float)cnt, 1.f);
    }
    __syncthreads();
    if (t < G * NC) {
        int g = t / NC, k = t % NC;
        float acc = 0.f;
        for (int c = 0; c < C; ++c) acc += sums[g * C + c] * lin_w[c * NC + k];
        out[t] = acc * inv[g] + lin_b[k];
    }
}

extern "C" void kernel_launch(void* const* d_in, const int* in_sizes, int n_in,
                              void* d_out, int out_size, void* d_ws, size_t ws_size,
                              hipStream_t stream)
{
    const float* x      = (const float*)d_in[0];
    const int*   eidx   = (const int*)d_in[1];
    const int*   batch  = (const int*)d_in[2];
    const float* W1     = (const float*)d_in[3];
    const float* att_s1 = (const float*)d_in[4];
    const float* att_d1 = (const float*)d_in[5];
    const float* b1     = (const float*)d_in[6];
    const float* W2     = (const float*)d_in[7];
    const float* att_s2 = (const float*)d_in[8];
    const float* att_d2 = (const float*)d_in[9];
    const float* b2     = (const float*)d_in[10];
    const float* lin_w  = (const float*)d_in[11];
    const float* lin_b  = (const float*)d_in[12];

    const int Nn  = in_sizes[2];         // 50000
    const int E   = in_sizes[1] / 2;     // 800000
    const int H1_ = 4, C1_ = 64, C2_ = 128, G = 32, NC = 5;
    const int D1 = H1_ * C1_;            // 256
    const int ET = E + Nn;               // edges + self loops
    const int K1 = 128, K2 = 256;

    const int* srcp = eidx;
    const int* dstp = eidx + E;

    float* ws = (float*)d_ws;
    size_t off = 0;
    auto alloc = [&](size_t n) { float* p = ws + off; off += n; return p; };
    float* h    = alloc((size_t)Nn * D1);   // h1; layer2 h2 occupies first Nn*C2
    float* o1   = alloc((size_t)Nn * D1);
    float* o2   = alloc((size_t)Nn * C2_);
    float* aS1  = alloc((size_t)Nn * H1_);
    float* aD1  = alloc((size_t)Nn * H1_);
    float* aS2  = alloc(Nn);
    float* aD2  = alloc(Nn);
    float* sums = alloc((size_t)G * C2_);
    unsigned short* BT1 = (unsigned short*)alloc(D1 * K1);        // 256 x 256 bf16
    unsigned short* BT2 = (unsigned short*)alloc(C2_ * K2);       // 128 x 512 bf16
    int* iws    = (int*)(ws + off);
    int* counts = iws;                      // Nn
    int* partial= iws + Nn;                 // Nn
    int* rowptr = iws + 2 * Nn;             // Nn+1
    int* cursor = iws + 3 * Nn + 1;         // Nn
    int* bsum   = iws + 4 * Nn + 1;         // <=256
    int* esrc   = iws + 4 * Nn + 1 + 256;   // ET

    const int NB = (Nn + 255) / 256;
    const int GB = (Nn + 63) / 64;          // gemm blocks (BM=64)

    // ---------------- CSR build (shared by both layers) ----------------
    hipMemsetAsync(counts, 0, (size_t)Nn * 4, stream);
    count_k<<<(ET + 255) / 256, 256, 0, stream>>>(dstp, counts, E, Nn);
    scan1_k<<<NB, 256, 0, stream>>>(counts, partial, bsum, Nn);
    scan2_k<<<1, 256, 0, stream>>>(bsum, NB);
    scan3_k<<<(Nn + 256) / 256, 256, 0, stream>>>(partial, bsum, rowptr, cursor, Nn, ET);
    build_k<<<(ET + 255) / 256, 256, 0, stream>>>(srcp, dstp, cursor, esrc, E, Nn);

    // ---------------- weight split (bf16 hi/lo, transposed) ----------------
    convW_k<<<(D1 * K1 + 255) / 256, 256, 0, stream>>>(W1, BT1, K1, D1);
    convW_k<<<(C2_ * K2 + 255) / 256, 256, 0, stream>>>(W2, BT2, K2, C2_);

    // ---------------- layer 1 ----------------
    gemm_mfma<256, 128><<<GB, 256, 0, stream>>>(x, BT1, h, Nn);
    attn_scores<<<Nn * H1_, 64, 0, stream>>>(h, att_s1, att_d1, aS1, aD1, Nn, H1_, C1_);
    gather1_k<<<(Nn + 3) / 4, 256, 0, stream>>>(rowptr, esrc, h, aS1, aD1, b1, o1, Nn);

    // ---------------- layer 2 ----------------
    gemm_mfma<128, 256><<<GB, 256, 0, stream>>>(o1, BT2, h, Nn);
    attn_scores<<<Nn, 64, 0, stream>>>(h, att_s2, att_d2, aS2, aD2, Nn, 1, C2_);
    gather2_k<<<(Nn + 3) / 4, 256, 0, stream>>>(rowptr, esrc, h, aS2, aD2, o2, Nn);

    // ---------------- pool + classifier ----------------
    hipMemsetAsync(sums, 0, (size_t)G * C2_ * 4, stream);
    pool_k<<<GB, C2_, 0, stream>>>(o2, b2, batch, sums, Nn, C2_);
    final_k<<<1, 256, 0, stream>>>(sums, batch, lin_w, lin_b, (float*)d_out, Nn, G, C2_, NC);
}

// Round 9
// 428.438 us; speedup vs baseline: 4.3299x; 1.2575x over previous
//
#include <hip/hip_runtime.h>
#include <math.h>

#define NEG_SLOPE 0.2f

__device__ inline float lrelu(float x) { return x > 0.f ? x : NEG_SLOPE * x; }

// ---------------- bf16 split helpers (RNE) ----------------
__device__ inline unsigned short f2bf(float f) {
    unsigned u = __float_as_uint(f);
    unsigned r = (u + 0x7fffu + ((u >> 16) & 1u)) >> 16;
    return (unsigned short)r;
}
__device__ inline float bf2f(unsigned short h) {
    return __uint_as_float(((unsigned)h) << 16);
}

typedef __attribute__((ext_vector_type(8))) short s16x8;
typedef __attribute__((ext_vector_type(4))) float f32x4;
typedef __attribute__((ext_vector_type(4))) _Float16 h16x4;

// Split W1[K1,N1] and W2[K2,N2] fp32 into BT [N, 2K] bf16 (transposed, hi|lo)
__global__ void convW_k(const float* __restrict__ W1, const float* __restrict__ W2,
                        unsigned short* __restrict__ BT1, unsigned short* __restrict__ BT2)
{
    int i = blockIdx.x * blockDim.x + threadIdx.x;   // 65536 total
    const float* W; unsigned short* BT; int K, N, idx;
    if (i < 32768) { W = W1; BT = BT1; K = 128; N = 256; idx = i; }
    else           { W = W2; BT = BT2; K = 256; N = 128; idx = i - 32768; }
    int n = idx / K, k = idx - n * K;
    float f = W[(size_t)k * N + n];
    unsigned short hi = f2bf(f);
    unsigned short lo = f2bf(f - bf2f(hi));
    BT[(size_t)n * (2 * K) + k] = hi;
    BT[(size_t)n * (2 * K) + K + k] = lo;
}

// ---- MFMA GEMM: C[M,N] = A[M,K] @ W[K,N] via bf16 hi/lo split (K'=2K) --------
template<int N, int K>
__launch_bounds__(256)
__global__ void gemm_mfma(const float* __restrict__ A, const unsigned short* __restrict__ BT,
                          float* __restrict__ C, int M)
{
    constexpr int ITERS = (2 * K) / 32;
    constexpr int WN = N / 4;
    constexpr int NT = WN / 16;
    constexpr int NCH = (N * 4) / 256;
    __shared__ unsigned short As[64 * 40] __attribute__((aligned(16)));
    __shared__ unsigned short Bs[N * 40] __attribute__((aligned(16)));
    const int t = threadIdx.x;
    const int wave = t >> 6, lane = t & 63;
    const int quad = lane >> 4, l15 = lane & 15;
    const int rowBase = blockIdx.x * 64;

    f32x4 acc[4][NT];
#pragma unroll
    for (int mi = 0; mi < 4; ++mi)
#pragma unroll
        for (int ni = 0; ni < NT; ++ni)
            acc[mi][ni] = (f32x4){0.f, 0.f, 0.f, 0.f};

    const int ar = t >> 2;
    const int ak = (t & 3) << 3;
    const int bc = (t * NCH) >> 2;
    const int bks = (t * NCH) & 3;

    for (int it = 0; it < ITERS; ++it) {
        const int kb = (it % (K / 32)) * 32;
        const bool lophase = (it * 32) >= K;
        {
            int gr = rowBase + ar;
            float f[8] = {0.f, 0.f, 0.f, 0.f, 0.f, 0.f, 0.f, 0.f};
            if (gr < M) {
                const float* ap = A + (size_t)gr * K + kb + ak;
                float4 v0 = *(const float4*)ap;
                float4 v1 = *(const float4*)(ap + 4);
                f[0] = v0.x; f[1] = v0.y; f[2] = v0.z; f[3] = v0.w;
                f[4] = v1.x; f[5] = v1.y; f[6] = v1.z; f[7] = v1.w;
            }
            s16x8 av;
#pragma unroll
            for (int j = 0; j < 8; ++j) {
                unsigned short hi = f2bf(f[j]);
                unsigned short o = lophase ? f2bf(f[j] - bf2f(hi)) : hi;
                av[j] = (short)o;
            }
            *(s16x8*)&As[ar * 40 + ak] = av;
        }
        {
            const unsigned short* bp = BT + (size_t)bc * (2 * K) + it * 32 + bks * 8;
            unsigned short* dp = &Bs[bc * 40 + bks * 8];
#pragma unroll
            for (int j = 0; j < NCH; ++j)
                *(s16x8*)(dp + j * 8) = *(const s16x8*)(bp + j * 8);
        }
        __syncthreads();
        s16x8 af[4], bfr[NT];
#pragma unroll
        for (int mi = 0; mi < 4; ++mi)
            af[mi] = *(const s16x8*)&As[(mi * 16 + l15) * 40 + quad * 8];
#pragma unroll
        for (int ni = 0; ni < NT; ++ni)
            bfr[ni] = *(const s16x8*)&Bs[(wave * WN + ni * 16 + l15) * 40 + quad * 8];
#pragma unroll
        for (int mi = 0; mi < 4; ++mi)
#pragma unroll
            for (int ni = 0; ni < NT; ++ni)
                acc[mi][ni] = __builtin_amdgcn_mfma_f32_16x16x32_bf16(
                    af[mi], bfr[ni], acc[mi][ni], 0, 0, 0);
        __syncthreads();
    }
#pragma unroll
    for (int mi = 0; mi < 4; ++mi) {
        int row = rowBase + mi * 16 + quad * 4;
#pragma unroll
        for (int r = 0; r < 4; ++r) {
            if (row + r < M) {
#pragma unroll
                for (int ni = 0; ni < NT; ++ni)
                    C[(size_t)(row + r) * N + wave * WN + ni * 16 + l15] = acc[mi][ni][r];
            }
        }
    }
}

// ==== prep layer 1: h fp32 -> fp16 copy + attn logits (H=4, C=64) ==============
// one wave per node; lane owns 4 channels; head = lane>>4; att index = channel
__global__ void prep1_k(const float* __restrict__ h, _Float16* __restrict__ hb,
                        const float* __restrict__ att_s, const float* __restrict__ att_d,
                        float* __restrict__ aS, float* __restrict__ aD, int Nn)
{
    int n = blockIdx.x * 4 + (threadIdx.x >> 6);
    int lane = threadIdx.x & 63;
    if (n >= Nn) return;
    int c4 = lane << 2;
    int head = lane >> 4;
    float4 v = *(const float4*)&h[(size_t)n * 256 + c4];
    h16x4 o;
    o[0] = (_Float16)v.x; o[1] = (_Float16)v.y;
    o[2] = (_Float16)v.z; o[3] = (_Float16)v.w;
    *(h16x4*)&hb[(size_t)n * 256 + c4] = o;
    float4 as = *(const float4*)&att_s[c4];
    float4 ad = *(const float4*)&att_d[c4];
    float ss = v.x * as.x + v.y * as.y + v.z * as.z + v.w * as.w;
    float sd = v.x * ad.x + v.y * ad.y + v.z * ad.z + v.w * ad.w;
#pragma unroll
    for (int off = 8; off > 0; off >>= 1) {
        ss += __shfl_xor(ss, off);
        sd += __shfl_xor(sd, off);
    }
    if ((lane & 15) == 0) {
        aS[n * 4 + head] = ss;
        aD[n * 4 + head] = sd;
    }
}

// ==== prep layer 2: h fp32 -> fp16 + attn logits (H=1, C=128) ==================
// half-wave per node (32 lanes x 4 channels)
__global__ void prep2_k(const float* __restrict__ h, _Float16* __restrict__ hb,
                        const float* __restrict__ att_s, const float* __restrict__ att_d,
                        float* __restrict__ aS, float* __restrict__ aD, int Nn)
{
    int n = blockIdx.x * 8 + ((threadIdx.x >> 6) << 1) + ((threadIdx.x & 63) >> 5);
    int l = threadIdx.x & 31;
    if (n >= Nn) return;
    int c4 = l << 2;
    float4 v = *(const float4*)&h[(size_t)n * 128 + c4];
    h16x4 o;
    o[0] = (_Float16)v.x; o[1] = (_Float16)v.y;
    o[2] = (_Float16)v.z; o[3] = (_Float16)v.w;
    *(h16x4*)&hb[(size_t)n * 128 + c4] = o;
    float4 as = *(const float4*)&att_s[c4];
    float4 ad = *(const float4*)&att_d[c4];
    float ss = v.x * as.x + v.y * as.y + v.z * as.z + v.w * as.w;
    float sd = v.x * ad.x + v.y * ad.y + v.z * ad.z + v.w * ad.w;
#pragma unroll
    for (int off = 16; off > 0; off >>= 1) {
        ss += __shfl_xor(ss, off);
        sd += __shfl_xor(sd, off);
    }
    if (l == 0) { aS[n] = ss; aD[n] = sd; }
}

// =================== CSR build (dst-bucketed edge list) =========================
__global__ void count_k(const int* __restrict__ dst, int* __restrict__ counts, int E, int Nn)
{
    int e = blockIdx.x * blockDim.x + threadIdx.x;
    if (e >= E + Nn) return;
    int d = (e < E) ? dst[e] : (e - E);
    atomicAdd(&counts[d], 1);
}

__global__ void scan1_k(const int* __restrict__ counts, int* __restrict__ partial,
                        int* __restrict__ bsum, int Nn)
{
    __shared__ int sh[256];
    int i = blockIdx.x * 256 + threadIdx.x;
    int v = (i < Nn) ? counts[i] : 0;
    sh[threadIdx.x] = v;
    __syncthreads();
#pragma unroll
    for (int o = 1; o < 256; o <<= 1) {
        int t = (threadIdx.x >= o) ? sh[threadIdx.x - o] : 0;
        __syncthreads();
        sh[threadIdx.x] += t;
        __syncthreads();
    }
    if (i < Nn) partial[i] = sh[threadIdx.x] - v;
    if (threadIdx.x == 255) bsum[blockIdx.x] = sh[255];
}

__global__ void scan2_k(int* __restrict__ bsum, int nb)
{
    __shared__ int sh[256];
    int v = (threadIdx.x < nb) ? bsum[threadIdx.x] : 0;
    sh[threadIdx.x] = v;
    __syncthreads();
#pragma unroll
    for (int o = 1; o < 256; o <<= 1) {
        int t = (threadIdx.x >= o) ? sh[threadIdx.x - o] : 0;
        __syncthreads();
        sh[threadIdx.x] += t;
        __syncthreads();
    }
    if (threadIdx.x < nb) bsum[threadIdx.x] = sh[threadIdx.x] - v;
}

__global__ void scan3_k(const int* __restrict__ partial, const int* __restrict__ bsum,
                        int* __restrict__ rowptr, int* __restrict__ cursor, int Nn, int ET)
{
    int i = blockIdx.x * 256 + threadIdx.x;
    if (i < Nn) {
        int v = partial[i] + bsum[i >> 8];
        rowptr[i] = v;
        cursor[i] = v;
    }
    if (i == Nn) rowptr[Nn] = ET;
}

__global__ void build_k(const int* __restrict__ src, const int* __restrict__ dst,
                        int* __restrict__ cursor, int* __restrict__ esrc, int E, int Nn)
{
    int e = blockIdx.x * blockDim.x + threadIdx.x;
    if (e >= E + Nn) return;
    int s, d;
    if (e < E) { s = src[e]; d = dst[e]; } else { s = e - E; d = s; }
    int pos = atomicAdd(&cursor[d], 1);
    esrc[pos] = s;
}

// ===== gather layer 1, fp16 h, online softmax, 8-edge unroll ===================
__global__ void gather1_k(const int* __restrict__ rp, const int* __restrict__ esrc,
                          const _Float16* __restrict__ hb, const float* __restrict__ aS,
                          const float* __restrict__ aD, const float* __restrict__ bias,
                          float* __restrict__ out, int Nn)
{
    int d = blockIdx.x * 4 + (threadIdx.x >> 6);
    int lane = threadIdx.x & 63;
    if (d >= Nn) return;
    int c4 = lane << 2;
    int head = lane >> 4;
    int p0 = rp[d], p1 = rp[d + 1];
    float adh = aD[d * 4 + head];
    const float* aSh = aS + head;
    float m = -1e30f, den = 0.f;
    float ax = 0.f, ay = 0.f, az = 0.f, aw = 0.f;
    int p = p0;
    for (; p + 8 <= p1; p += 8) {
        int s[8];
        float l[8];
#pragma unroll
        for (int j = 0; j < 8; ++j) s[j] = esrc[p + j];
#pragma unroll
        for (int j = 0; j < 8; ++j) l[j] = lrelu(aSh[s[j] * 4] + adh);
        float lm = l[0];
#pragma unroll
        for (int j = 1; j < 8; ++j) lm = fmaxf(lm, l[j]);
        if (lm > m) {
            float r = __expf(m - lm);
            ax *= r; ay *= r; az *= r; aw *= r; den *= r;
            m = lm;
        }
        h16x4 v[8];
#pragma unroll
        for (int j = 0; j < 8; ++j) v[j] = *(const h16x4*)&hb[(size_t)s[j] * 256 + c4];
#pragma unroll
        for (int j = 0; j < 8; ++j) {
            float w = __expf(l[j] - m);
            den += w;
            ax += (float)v[j][0] * w;
            ay += (float)v[j][1] * w;
            az += (float)v[j][2] * w;
            aw += (float)v[j][3] * w;
        }
    }
    for (; p < p1; ++p) {
        int s0 = esrc[p];
        float l0 = lrelu(aSh[s0 * 4] + adh);
        if (l0 > m) {
            float r = __expf(m - l0);
            ax *= r; ay *= r; az *= r; aw *= r; den *= r;
            m = l0;
        }
        float w0 = __expf(l0 - m);
        den += w0;
        h16x4 v0 = *(const h16x4*)&hb[(size_t)s0 * 256 + c4];
        ax += (float)v0[0] * w0; ay += (float)v0[1] * w0;
        az += (float)v0[2] * w0; aw += (float)v0[3] * w0;
    }
    float inv = 1.f / (den + 1e-16f);
    float4 b4 = *(const float4*)&bias[c4];
    float4 r;
    r.x = ax * inv + b4.x; r.x = r.x > 0.f ? r.x : expm1f(r.x);
    r.y = ay * inv + b4.y; r.y = r.y > 0.f ? r.y : expm1f(r.y);
    r.z = az * inv + b4.z; r.z = r.z > 0.f ? r.z : expm1f(r.z);
    r.w = aw * inv + b4.w; r.w = r.w > 0.f ? r.w : expm1f(r.w);
    *(float4*)&out[(size_t)d * 256 + c4] = r;
}

// ===== gather layer 2, fp16 h, online softmax, half-waves, 4-edge unroll =======
__global__ void gather2_k(const int* __restrict__ rp, const int* __restrict__ esrc,
                          const _Float16* __restrict__ hb, const float* __restrict__ aS,
                          const float* __restrict__ aD, float* __restrict__ out, int Nn)
{
    int d = blockIdx.x * 4 + (threadIdx.x >> 6);
    int lane = threadIdx.x & 63;
    if (d >= Nn) return;
    int half = lane >> 5;
    int c4 = (lane & 31) << 2;
    int p0 = rp[d], p1 = rp[d + 1];
    float adh = aD[d];
    float m = -1e30f, den = 0.f;
    float ax = 0.f, ay = 0.f, az = 0.f, aw = 0.f;
    int p = p0 + half;
    for (; p + 6 < p1; p += 8) {
        int s[4];
        float l[4];
#pragma unroll
        for (int j = 0; j < 4; ++j) s[j] = esrc[p + 2 * j];
#pragma unroll
        for (int j = 0; j < 4; ++j) l[j] = lrelu(aS[s[j]] + adh);
        float lm = fmaxf(fmaxf(l[0], l[1]), fmaxf(l[2], l[3]));
        if (lm > m) {
            float r = __expf(m - lm);
            ax *= r; ay *= r; az *= r; aw *= r; den *= r;
            m = lm;
        }
        h16x4 v[4];
#pragma unroll
        for (int j = 0; j < 4; ++j) v[j] = *(const h16x4*)&hb[(size_t)s[j] * 128 + c4];
#pragma unroll
        for (int j = 0; j < 4; ++j) {
            float w = __expf(l[j] - m);
            den += w;
            ax += (float)v[j][0] * w;
            ay += (float)v[j][1] * w;
            az += (float)v[j][2] * w;
            aw += (float)v[j][3] * w;
        }
    }
    for (; p < p1; p += 2) {
        int s0 = esrc[p];
        float l0 = lrelu(aS[s0] + adh);
        if (l0 > m) {
            float r = __expf(m - l0);
            ax *= r; ay *= r; az *= r; aw *= r; den *= r;
            m = l0;
        }
        float w0 = __expf(l0 - m);
        den += w0;
        h16x4 v0 = *(const h16x4*)&hb[(size_t)s0 * 128 + c4];
        ax += (float)v0[0] * w0; ay += (float)v0[1] * w0;
        az += (float)v0[2] * w0; aw += (float)v0[3] * w0;
    }
    // merge halves: rescale to common max, then sum
    float mo = __shfl_xor(m, 32);
    float mm = fmaxf(m, mo);
    float fsc = __expf(m - mm);
    ax *= fsc; ay *= fsc; az *= fsc; aw *= fsc; den *= fsc;
    ax += __shfl_xor(ax, 32);
    ay += __shfl_xor(ay, 32);
    az += __shfl_xor(az, 32);
    aw += __shfl_xor(aw, 32);
    den += __shfl_xor(den, 32);
    float inv = 1.f / (den + 1e-16f);
    if (half == 0)
        *(float4*)&out[(size_t)d * 128 + c4] =
            make_float4(ax * inv, ay * inv, az * inv, aw * inv);
}

// batch is sorted; per-block run-length accumulate then atomicAdd per graph run
__global__ void pool_k(const float* __restrict__ o2, const float* __restrict__ b2,
                       const int* __restrict__ batch, float* __restrict__ sums, int Nn, int C)
{
    int c = threadIdx.x;               // C = 128
    int n0 = blockIdx.x * 64;
    int n1 = min(n0 + 64, Nn);
    float local = 0.f;
    int gcur = batch[n0];
    float bc = b2[c];
    for (int n = n0; n < n1; ++n) {
        int g = batch[n];
        if (g != gcur) {
            atomicAdd(&sums[gcur * C + c], local);
            local = 0.f;
            gcur = g;
        }
        float v = o2[(size_t)n * C + c] + bc;
        local += v > 0.f ? v : expm1f(v);
    }
    atomicAdd(&sums[gcur * C + c], local);
}

__global__ void final_k(const float* __restrict__ sums, const int* __restrict__ batch,
                        const float* __restrict__ lin_w, const float* __restrict__ lin_b,
                        float* __restrict__ out, int Nn, int G, int C, int NC)
{
    __shared__ float inv[64];
    int t = threadIdx.x;
    if (t < G) {
        int lo = 0, hi = Nn;
        while (lo < hi) { int mid = (lo + hi) >> 1; if (batch[mid] < t) lo = mid + 1; else hi = mid; }
        int lb = lo;
        lo = 0; hi = Nn;
        while (lo < hi) { int mid = (lo + hi) >> 1; if (batch[mid] < t + 1) lo = mid + 1; else hi = mid; }
        int cnt = lo - lb;
        inv[t] = 1.f / fmaxf((float)cnt, 1.f);
    }
    __syncthreads();
    if (t < G * NC) {
        int g = t / NC, k = t % NC;
        float acc = 0.f;
        for (int c = 0; c < C; ++c) acc += sums[g * C + c] * lin_w[c * NC + k];
        out[t] = acc * inv[g] + lin_b[k];
    }
}

extern "C" void kernel_launch(void* const* d_in, const int* in_sizes, int n_in,
                              void* d_out, int out_size, void* d_ws, size_t ws_size,
                              hipStream_t stream)
{
    const float* x      = (const float*)d_in[0];
    const int*   eidx   = (const int*)d_in[1];
    const int*   batch  = (const int*)d_in[2];
    const float* W1     = (const float*)d_in[3];
    const float* att_s1 = (const float*)d_in[4];
    const float* att_d1 = (const float*)d_in[5];
    const float* b1     = (const float*)d_in[6];
    const float* W2     = (const float*)d_in[7];
    const float* att_s2 = (const float*)d_in[8];
    const float* att_d2 = (const float*)d_in[9];
    const float* b2     = (const float*)d_in[10];
    const float* lin_w  = (const float*)d_in[11];
    const float* lin_b  = (const float*)d_in[12];

    const int Nn  = in_sizes[2];         // 50000
    const int E   = in_sizes[1] / 2;     // 800000
    const int H1_ = 4, C1_ = 64, C2_ = 128, G = 32, NC = 5;
    const int D1 = H1_ * C1_;            // 256
    const int ET = E + Nn;
    const int K1 = 128, K2 = 256;

    const int* srcp = eidx;
    const int* dstp = eidx + E;

    float* ws = (float*)d_ws;
    size_t off = 0;
    auto alloc = [&](size_t n) { float* p = ws + off; off += n; return p; };
    float* h    = alloc((size_t)Nn * D1);   // fp32 GEMM out (both layers)
    float* o1   = alloc((size_t)Nn * D1);
    float* o2   = alloc((size_t)Nn * C2_);
    float* aS1  = alloc((size_t)Nn * H1_);
    float* aD1  = alloc((size_t)Nn * H1_);
    float* aS2  = alloc(Nn);
    float* aD2  = alloc(Nn);
    float* sums = alloc((size_t)G * C2_);
    unsigned short* BT1 = (unsigned short*)alloc(D1 * K1);
    unsigned short* BT2 = (unsigned short*)alloc(C2_ * K2);
    _Float16* hb1 = (_Float16*)alloc((size_t)Nn * D1 / 2);    // fp16 copy of h1
    _Float16* hb2 = (_Float16*)alloc((size_t)Nn * C2_ / 2);   // fp16 copy of h2
    int* iws    = (int*)(ws + off);
    int* counts = iws;
    int* partial= iws + Nn;
    int* rowptr = iws + 2 * Nn;
    int* cursor = iws + 3 * Nn + 1;
    int* bsum   = iws + 4 * Nn + 1;
    int* esrc   = iws + 4 * Nn + 1 + 256;

    const int NB = (Nn + 255) / 256;
    const int GB = (Nn + 63) / 64;

    // ---------------- CSR build (shared by both layers) ----------------
    hipMemsetAsync(counts, 0, (size_t)Nn * 4, stream);
    count_k<<<(ET + 255) / 256, 256, 0, stream>>>(dstp, counts, E, Nn);
    scan1_k<<<NB, 256, 0, stream>>>(counts, partial, bsum, Nn);
    scan2_k<<<1, 256, 0, stream>>>(bsum, NB);
    scan3_k<<<(Nn + 256) / 256, 256, 0, stream>>>(partial, bsum, rowptr, cursor, Nn, ET);
    build_k<<<(ET + 255) / 256, 256, 0, stream>>>(srcp, dstp, cursor, esrc, E, Nn);

    // ---------------- weight split (bf16 hi/lo, transposed) ----------------
    convW_k<<<256, 256, 0, stream>>>(W1, W2, BT1, BT2);

    // ---------------- layer 1 ----------------
    gemm_mfma<256, 128><<<GB, 256, 0, stream>>>(x, BT1, h, Nn);
    prep1_k<<<(Nn + 3) / 4, 256, 0, stream>>>(h, hb1, att_s1, att_d1, aS1, aD1, Nn);
    gather1_k<<<(Nn + 3) / 4, 256, 0, stream>>>(rowptr, esrc, hb1, aS1, aD1, b1, o1, Nn);

    // ---------------- layer 2 ----------------
    gemm_mfma<128, 256><<<GB, 256, 0, stream>>>(o1, BT2, h, Nn);
    prep2_k<<<(Nn + 7) / 8, 256, 0, stream>>>(h, hb2, att_s2, att_d2, aS2, aD2, Nn);
    gather2_k<<<(Nn + 3) / 4, 256, 0, stream>>>(rowptr, esrc, hb2, aS2, aD2, o2, Nn);

    // ---------------- pool + classifier ----------------
    hipMemsetAsync(sums, 0, (size_t)G * C2_ * 4, stream);
    pool_k<<<GB, C2_, 0, stream>>>(o2, b2, batch, sums, Nn, C2_);
    final_k<<<1, 256, 0, stream>>>(sums, batch, lin_w, lin_b, (float*)d_out, Nn, G, C2_, NC);
}

// Round 10
// 413.399 us; speedup vs baseline: 4.4874x; 1.0364x over previous
//
#include <hip/hip_runtime.h>
#include <math.h>

#define NEG_SLOPE 0.2f

__device__ inline float lrelu(float x) { return x > 0.f ? x : NEG_SLOPE * x; }

// ---------------- bf16 split helpers (RNE) ----------------
__device__ inline unsigned short f2bf(float f) {
    unsigned u = __float_as_uint(f);
    unsigned r = (u + 0x7fffu + ((u >> 16) & 1u)) >> 16;
    return (unsigned short)r;
}
__device__ inline float bf2f(unsigned short h) {
    return __uint_as_float(((unsigned)h) << 16);
}

typedef __attribute__((ext_vector_type(8))) short s16x8;
typedef __attribute__((ext_vector_type(4))) float f32x4;
typedef __attribute__((ext_vector_type(4))) _Float16 h16x4;

// Split W1[K1,N1] and W2[K2,N2] fp32 into BT [N, 2K] bf16 (transposed, hi|lo)
__global__ void convW_k(const float* __restrict__ W1, const float* __restrict__ W2,
                        unsigned short* __restrict__ BT1, unsigned short* __restrict__ BT2)
{
    int i = blockIdx.x * blockDim.x + threadIdx.x;   // 65536 total
    const float* W; unsigned short* BT; int K, N, idx;
    if (i < 32768) { W = W1; BT = BT1; K = 128; N = 256; idx = i; }
    else           { W = W2; BT = BT2; K = 256; N = 128; idx = i - 32768; }
    int n = idx / K, k = idx - n * K;
    float f = W[(size_t)k * N + n];
    unsigned short hi = f2bf(f);
    unsigned short lo = f2bf(f - bf2f(hi));
    BT[(size_t)n * (2 * K) + k] = hi;
    BT[(size_t)n * (2 * K) + K + k] = lo;
}

// ---- Fused MFMA GEMM + fp16 out + attention logits ---------------------------
// C-equivalent = A[M,K] @ W[K,N] via bf16 hi/lo split; epilogue writes HB (fp16)
// and per-row attn logits aS/aD (H=4: direct store, head=wave; H=1: atomicAdd).
template<int N, int K, int H>
__launch_bounds__(256)
__global__ void gemm_fused(const float* __restrict__ A, const unsigned short* __restrict__ BT,
                           _Float16* __restrict__ HB, const float* __restrict__ att_s,
                           const float* __restrict__ att_d, float* __restrict__ aS,
                           float* __restrict__ aD, int M)
{
    constexpr int ITERS = (2 * K) / 32;
    constexpr int WN = N / 4;
    constexpr int NT = WN / 16;
    constexpr int NCH = (N * 4) / 256;
    __shared__ unsigned short As[64 * 40] __attribute__((aligned(16)));
    __shared__ unsigned short Bs[N * 40] __attribute__((aligned(16)));
    const int t = threadIdx.x;
    const int wave = t >> 6, lane = t & 63;
    const int quad = lane >> 4, l15 = lane & 15;
    const int rowBase = blockIdx.x * 64;

    f32x4 acc[4][NT];
#pragma unroll
    for (int mi = 0; mi < 4; ++mi)
#pragma unroll
        for (int ni = 0; ni < NT; ++ni)
            acc[mi][ni] = (f32x4){0.f, 0.f, 0.f, 0.f};

    const int ar = t >> 2;
    const int ak = (t & 3) << 3;
    const int bc = (t * NCH) >> 2;
    const int bks = (t * NCH) & 3;

    for (int it = 0; it < ITERS; ++it) {
        const int kb = (it % (K / 32)) * 32;
        const bool lophase = (it * 32) >= K;
        {
            int gr = rowBase + ar;
            float f[8] = {0.f, 0.f, 0.f, 0.f, 0.f, 0.f, 0.f, 0.f};
            if (gr < M) {
                const float* ap = A + (size_t)gr * K + kb + ak;
                float4 v0 = *(const float4*)ap;
                float4 v1 = *(const float4*)(ap + 4);
                f[0] = v0.x; f[1] = v0.y; f[2] = v0.z; f[3] = v0.w;
                f[4] = v1.x; f[5] = v1.y; f[6] = v1.z; f[7] = v1.w;
            }
            s16x8 av;
#pragma unroll
            for (int j = 0; j < 8; ++j) {
                unsigned short hi = f2bf(f[j]);
                unsigned short o = lophase ? f2bf(f[j] - bf2f(hi)) : hi;
                av[j] = (short)o;
            }
            *(s16x8*)&As[ar * 40 + ak] = av;
        }
        {
            const unsigned short* bp = BT + (size_t)bc * (2 * K) + it * 32 + bks * 8;
            unsigned short* dp = &Bs[bc * 40 + bks * 8];
#pragma unroll
            for (int j = 0; j < NCH; ++j)
                *(s16x8*)(dp + j * 8) = *(const s16x8*)(bp + j * 8);
        }
        __syncthreads();
        s16x8 af[4], bfr[NT];
#pragma unroll
        for (int mi = 0; mi < 4; ++mi)
            af[mi] = *(const s16x8*)&As[(mi * 16 + l15) * 40 + quad * 8];
#pragma unroll
        for (int ni = 0; ni < NT; ++ni)
            bfr[ni] = *(const s16x8*)&Bs[(wave * WN + ni * 16 + l15) * 40 + quad * 8];
#pragma unroll
        for (int mi = 0; mi < 4; ++mi)
#pragma unroll
            for (int ni = 0; ni < NT; ++ni)
                acc[mi][ni] = __builtin_amdgcn_mfma_f32_16x16x32_bf16(
                    af[mi], bfr[ni], acc[mi][ni], 0, 0, 0);
        __syncthreads();
    }
    // ---- epilogue: fp16 store + logits. D layout col=lane&15, row=quad*4+reg
    float asv[NT], adv[NT];
#pragma unroll
    for (int ni = 0; ni < NT; ++ni) {
        int col = wave * WN + ni * 16 + l15;
        asv[ni] = att_s[col];
        adv[ni] = att_d[col];
    }
#pragma unroll
    for (int mi = 0; mi < 4; ++mi) {
#pragma unroll
        for (int r = 0; r < 4; ++r) {
            int row = rowBase + mi * 16 + quad * 4 + r;
            bool ok = row < M;
            float ss = 0.f, sd = 0.f;
#pragma unroll
            for (int ni = 0; ni < NT; ++ni) {
                float v = acc[mi][ni][r];
                ss += v * asv[ni];
                sd += v * adv[ni];
                if (ok)
                    HB[(size_t)row * N + wave * WN + ni * 16 + l15] = (_Float16)v;
            }
#pragma unroll
            for (int off = 8; off > 0; off >>= 1) {
                ss += __shfl_xor(ss, off);
                sd += __shfl_xor(sd, off);
            }
            if (ok && l15 == 0) {
                if (H == 4) {
                    aS[row * 4 + wave] = ss;
                    aD[row * 4 + wave] = sd;
                } else {
                    atomicAdd(&aS[row], ss);
                    atomicAdd(&aD[row], sd);
                }
            }
        }
    }
}

// =================== CSR build (dst-bucketed edge list) =========================
__global__ void count_k(const int* __restrict__ dst, int* __restrict__ counts, int E, int Nn)
{
    int e = blockIdx.x * blockDim.x + threadIdx.x;
    if (e >= E + Nn) return;
    int d = (e < E) ? dst[e] : (e - E);
    atomicAdd(&counts[d], 1);
}

__global__ void scan1_k(const int* __restrict__ counts, int* __restrict__ partial,
                        int* __restrict__ bsum, int Nn)
{
    __shared__ int sh[256];
    int i = blockIdx.x * 256 + threadIdx.x;
    int v = (i < Nn) ? counts[i] : 0;
    sh[threadIdx.x] = v;
    __syncthreads();
#pragma unroll
    for (int o = 1; o < 256; o <<= 1) {
        int t = (threadIdx.x >= o) ? sh[threadIdx.x - o] : 0;
        __syncthreads();
        sh[threadIdx.x] += t;
        __syncthreads();
    }
    if (i < Nn) partial[i] = sh[threadIdx.x] - v;
    if (threadIdx.x == 255) bsum[blockIdx.x] = sh[255];
}

__global__ void scan2_k(int* __restrict__ bsum, int nb)
{
    __shared__ int sh[256];
    int v = (threadIdx.x < nb) ? bsum[threadIdx.x] : 0;
    sh[threadIdx.x] = v;
    __syncthreads();
#pragma unroll
    for (int o = 1; o < 256; o <<= 1) {
        int t = (threadIdx.x >= o) ? sh[threadIdx.x - o] : 0;
        __syncthreads();
        sh[threadIdx.x] += t;
        __syncthreads();
    }
    if (threadIdx.x < nb) bsum[threadIdx.x] = sh[threadIdx.x] - v;
}

__global__ void scan3_k(const int* __restrict__ partial, const int* __restrict__ bsum,
                        int* __restrict__ rowptr, int* __restrict__ cursor, int Nn, int ET)
{
    int i = blockIdx.x * 256 + threadIdx.x;
    if (i < Nn) {
        int v = partial[i] + bsum[i >> 8];
        rowptr[i] = v;
        cursor[i] = v;
    }
    if (i == Nn) rowptr[Nn] = ET;
}

__global__ void build_k(const int* __restrict__ src, const int* __restrict__ dst,
                        int* __restrict__ cursor, int* __restrict__ esrc, int E, int Nn)
{
    int e = blockIdx.x * blockDim.x + threadIdx.x;
    if (e >= E + Nn) return;
    int s, d;
    if (e < E) { s = src[e]; d = dst[e]; } else { s = e - E; d = s; }
    int pos = atomicAdd(&cursor[d], 1);
    esrc[pos] = s;
}

// ===== gather layer 1, fp16 h, online softmax, 8-edge unroll ===================
__global__ void gather1_k(const int* __restrict__ rp, const int* __restrict__ esrc,
                          const _Float16* __restrict__ hb, const float* __restrict__ aS,
                          const float* __restrict__ aD, const float* __restrict__ bias,
                          float* __restrict__ out, int Nn)
{
    int d = blockIdx.x * 4 + (threadIdx.x >> 6);
    int lane = threadIdx.x & 63;
    if (d >= Nn) return;
    int c4 = lane << 2;
    int head = lane >> 4;
    int p0 = rp[d], p1 = rp[d + 1];
    float adh = aD[d * 4 + head];
    const float* aSh = aS + head;
    float m = -1e30f, den = 0.f;
    float ax = 0.f, ay = 0.f, az = 0.f, aw = 0.f;
    int p = p0;
    for (; p + 8 <= p1; p += 8) {
        int s[8];
        float l[8];
#pragma unroll
        for (int j = 0; j < 8; ++j) s[j] = esrc[p + j];
#pragma unroll
        for (int j = 0; j < 8; ++j) l[j] = lrelu(aSh[s[j] * 4] + adh);
        float lm = l[0];
#pragma unroll
        for (int j = 1; j < 8; ++j) lm = fmaxf(lm, l[j]);
        if (lm > m) {
            float r = __expf(m - lm);
            ax *= r; ay *= r; az *= r; aw *= r; den *= r;
            m = lm;
        }
        h16x4 v[8];
#pragma unroll
        for (int j = 0; j < 8; ++j) v[j] = *(const h16x4*)&hb[(size_t)s[j] * 256 + c4];
#pragma unroll
        for (int j = 0; j < 8; ++j) {
            float w = __expf(l[j] - m);
            den += w;
            ax += (float)v[j][0] * w;
            ay += (float)v[j][1] * w;
            az += (float)v[j][2] * w;
            aw += (float)v[j][3] * w;
        }
    }
    for (; p < p1; ++p) {
        int s0 = esrc[p];
        float l0 = lrelu(aSh[s0 * 4] + adh);
        if (l0 > m) {
            float r = __expf(m - l0);
            ax *= r; ay *= r; az *= r; aw *= r; den *= r;
            m = l0;
        }
        float w0 = __expf(l0 - m);
        den += w0;
        h16x4 v0 = *(const h16x4*)&hb[(size_t)s0 * 256 + c4];
        ax += (float)v0[0] * w0; ay += (float)v0[1] * w0;
        az += (float)v0[2] * w0; aw += (float)v0[3] * w0;
    }
    float inv = 1.f / (den + 1e-16f);
    float4 b4 = *(const float4*)&bias[c4];
    float4 r;
    r.x = ax * inv + b4.x; r.x = r.x > 0.f ? r.x : expm1f(r.x);
    r.y = ay * inv + b4.y; r.y = r.y > 0.f ? r.y : expm1f(r.y);
    r.z = az * inv + b4.z; r.z = r.z > 0.f ? r.z : expm1f(r.z);
    r.w = aw * inv + b4.w; r.w = r.w > 0.f ? r.w : expm1f(r.w);
    *(float4*)&out[(size_t)d * 256 + c4] = r;
}

// ===== gather layer 2, fp16 h, online softmax, half-waves, 4-edge unroll =======
__global__ void gather2_k(const int* __restrict__ rp, const int* __restrict__ esrc,
                          const _Float16* __restrict__ hb, const float* __restrict__ aS,
                          const float* __restrict__ aD, float* __restrict__ out, int Nn)
{
    int d = blockIdx.x * 4 + (threadIdx.x >> 6);
    int lane = threadIdx.x & 63;
    if (d >= Nn) return;
    int half = lane >> 5;
    int c4 = (lane & 31) << 2;
    int p0 = rp[d], p1 = rp[d + 1];
    float adh = aD[d];
    float m = -1e30f, den = 0.f;
    float ax = 0.f, ay = 0.f, az = 0.f, aw = 0.f;
    int p = p0 + half;
    for (; p + 6 < p1; p += 8) {
        int s[4];
        float l[4];
#pragma unroll
        for (int j = 0; j < 4; ++j) s[j] = esrc[p + 2 * j];
#pragma unroll
        for (int j = 0; j < 4; ++j) l[j] = lrelu(aS[s[j]] + adh);
        float lm = fmaxf(fmaxf(l[0], l[1]), fmaxf(l[2], l[3]));
        if (lm > m) {
            float r = __expf(m - lm);
            ax *= r; ay *= r; az *= r; aw *= r; den *= r;
            m = lm;
        }
        h16x4 v[4];
#pragma unroll
        for (int j = 0; j < 4; ++j) v[j] = *(const h16x4*)&hb[(size_t)s[j] * 128 + c4];
#pragma unroll
        for (int j = 0; j < 4; ++j) {
            float w = __expf(l[j] - m);
            den += w;
            ax += (float)v[j][0] * w;
            ay += (float)v[j][1] * w;
            az += (float)v[j][2] * w;
            aw += (float)v[j][3] * w;
        }
    }
    for (; p < p1; p += 2) {
        int s0 = esrc[p];
        float l0 = lrelu(aS[s0] + adh);
        if (l0 > m) {
            float r = __expf(m - l0);
            ax *= r; ay *= r; az *= r; aw *= r; den *= r;
            m = l0;
        }
        float w0 = __expf(l0 - m);
        den += w0;
        h16x4 v0 = *(const h16x4*)&hb[(size_t)s0 * 128 + c4];
        ax += (float)v0[0] * w0; ay += (float)v0[1] * w0;
        az += (float)v0[2] * w0; aw += (float)v0[3] * w0;
    }
    // merge halves: rescale to common max, then sum
    float mo = __shfl_xor(m, 32);
    float mm = fmaxf(m, mo);
    float fsc = __expf(m - mm);
    ax *= fsc; ay *= fsc; az *= fsc; aw *= fsc; den *= fsc;
    ax += __shfl_xor(ax, 32);
    ay += __shfl_xor(ay, 32);
    az += __shfl_xor(az, 32);
    aw += __shfl_xor(aw, 32);
    den += __shfl_xor(den, 32);
    float inv = 1.f / (den + 1e-16f);
    if (half == 0)
        *(float4*)&out[(size_t)d * 128 + c4] =
            make_float4(ax * inv, ay * inv, az * inv, aw * inv);
}

// batch is sorted; per-block run-length accumulate then atomicAdd per graph run
__global__ void pool_k(const float* __restrict__ o2, const float* __restrict__ b2,
                       const int* __restrict__ batch, float* __restrict__ sums, int Nn, int C)
{
    int c = threadIdx.x;               // C = 128
    int n0 = blockIdx.x * 64;
    int n1 = min(n0 + 64, Nn);
    float local = 0.f;
    int gcur = batch[n0];
    float bc = b2[c];
    for (int n = n0; n < n1; ++n) {
        int g = batch[n];
        if (g != gcur) {
            atomicAdd(&sums[gcur * C + c], local);
            local = 0.f;
            gcur = g;
        }
        float v = o2[(size_t)n * C + c] + bc;
        local += v > 0.f ? v : expm1f(v);
    }
    atomicAdd(&sums[gcur * C + c], local);
}

__global__ void final_k(const float* __restrict__ sums, const int* __restrict__ batch,
                        const float* __restrict__ lin_w, const float* __restrict__ lin_b,
                        float* __restrict__ out, int Nn, int G, int C, int NC)
{
    __shared__ float inv[64];
    int t = threadIdx.x;
    if (t < G) {
        int lo = 0, hi = Nn;
        while (lo < hi) { int mid = (lo + hi) >> 1; if (batch[mid] < t) lo = mid + 1; else hi = mid; }
        int lb = lo;
        lo = 0; hi = Nn;
        while (lo < hi) { int mid = (lo + hi) >> 1; if (batch[mid] < t + 1) lo = mid + 1; else hi = mid; }
        int cnt = lo - lb;
        inv[t] = 1.f / fmaxf((float)cnt, 1.f);
    }
    __syncthreads();
    if (t < G * NC) {
        int g = t / NC, k = t % NC;
        float acc = 0.f;
        for (int c = 0; c < C; ++c) acc += sums[g * C + c] * lin_w[c * NC + k];
        out[t] = acc * inv[g] + lin_b[k];
    }
}

extern "C" void kernel_launch(void* const* d_in, const int* in_sizes, int n_in,
                              void* d_out, int out_size, void* d_ws, size_t ws_size,
                              hipStream_t stream)
{
    const float* x      = (const float*)d_in[0];
    const int*   eidx   = (const int*)d_in[1];
    const int*   batch  = (const int*)d_in[2];
    const float* W1     = (const float*)d_in[3];
    const float* att_s1 = (const float*)d_in[4];
    const float* att_d1 = (const float*)d_in[5];
    const float* b1     = (const float*)d_in[6];
    const float* W2     = (const float*)d_in[7];
    const float* att_s2 = (const float*)d_in[8];
    const float* att_d2 = (const float*)d_in[9];
    const float* b2     = (const float*)d_in[10];
    const float* lin_w  = (const float*)d_in[11];
    const float* lin_b  = (const float*)d_in[12];

    const int Nn  = in_sizes[2];         // 50000
    const int E   = in_sizes[1] / 2;     // 800000
    const int H1_ = 4, C1_ = 64, C2_ = 128, G = 32, NC = 5;
    const int D1 = H1_ * C1_;            // 256
    const int ET = E + Nn;

    const int* srcp = eidx;
    const int* dstp = eidx + E;

    float* ws = (float*)d_ws;
    size_t off = 0;
    auto alloc = [&](size_t n) { float* p = ws + off; off += n; return p; };
    float* o1   = alloc((size_t)Nn * D1);
    float* o2   = alloc((size_t)Nn * C2_);
    float* aS1  = alloc((size_t)Nn * H1_);
    float* aD1  = alloc((size_t)Nn * H1_);
    float* aS2  = alloc(Nn);              // contiguous with aD2 for single memset
    float* aD2  = alloc(Nn);
    float* sums = alloc((size_t)G * C2_);
    unsigned short* BT1 = (unsigned short*)alloc(D1 * 128);
    unsigned short* BT2 = (unsigned short*)alloc(C2_ * 256);
    _Float16* hb1 = (_Float16*)alloc((size_t)Nn * D1 / 2);    // fp16 h1
    _Float16* hb2 = (_Float16*)alloc((size_t)Nn * C2_ / 2);   // fp16 h2
    int* iws    = (int*)(ws + off);
    int* counts = iws;
    int* partial= iws + Nn;
    int* rowptr = iws + 2 * Nn;
    int* cursor = iws + 3 * Nn + 1;
    int* bsum   = iws + 4 * Nn + 1;
    int* esrc   = iws + 4 * Nn + 1 + 256;

    const int NB = (Nn + 255) / 256;
    const int GB = (Nn + 63) / 64;

    // ---------------- CSR build (shared by both layers) ----------------
    hipMemsetAsync(counts, 0, (size_t)Nn * 4, stream);
    hipMemsetAsync(aS2, 0, (size_t)2 * Nn * 4, stream);   // aS2+aD2 (gemm2 atomics)
    count_k<<<(ET + 255) / 256, 256, 0, stream>>>(dstp, counts, E, Nn);
    scan1_k<<<NB, 256, 0, stream>>>(counts, partial, bsum, Nn);
    scan2_k<<<1, 256, 0, stream>>>(bsum, NB);
    scan3_k<<<(Nn + 256) / 256, 256, 0, stream>>>(partial, bsum, rowptr, cursor, Nn, ET);
    build_k<<<(ET + 255) / 256, 256, 0, stream>>>(srcp, dstp, cursor, esrc, E, Nn);

    // ---------------- weight split (bf16 hi/lo, transposed) ----------------
    convW_k<<<256, 256, 0, stream>>>(W1, W2, BT1, BT2);

    // ---------------- layer 1: GEMM + fp16 + logits fused ----------------
    gemm_fused<256, 128, 4><<<GB, 256, 0, stream>>>(x, BT1, hb1, att_s1, att_d1,
                                                    aS1, aD1, Nn);
    gather1_k<<<(Nn + 3) / 4, 256, 0, stream>>>(rowptr, esrc, hb1, aS1, aD1, b1, o1, Nn);

    // ---------------- layer 2: GEMM + fp16 + logits fused ----------------
    gemm_fused<128, 256, 1><<<GB, 256, 0, stream>>>(o1, BT2, hb2, att_s2, att_d2,
                                                    aS2, aD2, Nn);
    gather2_k<<<(Nn + 3) / 4, 256, 0, stream>>>(rowptr, esrc, hb2, aS2, aD2, o2, Nn);

    // ---------------- pool + classifier ----------------
    hipMemsetAsync(sums, 0, (size_t)G * C2_ * 4, stream);
    pool_k<<<GB, C2_, 0, stream>>>(o2, b2, batch, sums, Nn, C2_);
    final_k<<<1, 256, 0, stream>>>(sums, batch, lin_w, lin_b, (float*)d_out, Nn, G, C2_, NC);
}

// Round 11
// 403.837 us; speedup vs baseline: 4.5937x; 1.0237x over previous
//
#include <hip/hip_runtime.h>
#include <math.h>

#define NEG_SLOPE 0.2f

__device__ inline float lrelu(float x) { return x > 0.f ? x : NEG_SLOPE * x; }

typedef __attribute__((ext_vector_type(8))) _Float16 f16x8;
typedef __attribute__((ext_vector_type(4))) float f32x4;
typedef __attribute__((ext_vector_type(4))) _Float16 h16x4;

// Convert W1[K1,N1], W2[K2,N2] fp32 -> BT [N][K] fp16 (transposed)
__global__ void convW_k(const float* __restrict__ W1, const float* __restrict__ W2,
                        _Float16* __restrict__ BT1, _Float16* __restrict__ BT2)
{
    int i = blockIdx.x * blockDim.x + threadIdx.x;   // 65536 total
    if (i < 32768) {
        int n = i >> 7, k = i & 127;                 // K=128, N=256
        BT1[(size_t)n * 128 + k] = (_Float16)W1[(size_t)k * 256 + n];
    } else {
        int idx = i - 32768;
        int n = idx >> 8, k = idx & 255;             // K=256, N=128
        BT2[(size_t)n * 256 + k] = (_Float16)W2[(size_t)k * 128 + n];
    }
}

// ---- Fused fp16 MFMA GEMM + fp16 out + attention logits ----------------------
// C = A[M,K] @ W[K,N] (fp16 inputs, fp32 acc); epilogue writes HB (fp16) and
// per-row attn logits aS/aD (H=4: direct store head=wave; H=1: atomicAdd).
template<int N, int K, int H>
__launch_bounds__(256)
__global__ void gemm_fused(const float* __restrict__ A, const _Float16* __restrict__ BT,
                           _Float16* __restrict__ HB, const float* __restrict__ att_s,
                           const float* __restrict__ att_d, float* __restrict__ aS,
                           float* __restrict__ aD, int M)
{
    constexpr int ITERS = K / 32;
    constexpr int WN = N / 4;
    constexpr int NT = WN / 16;
    constexpr int NCH = (N * 4) / 256;
    __shared__ unsigned short As[64 * 40] __attribute__((aligned(16)));
    __shared__ unsigned short Bs[N * 40] __attribute__((aligned(16)));
    const int t = threadIdx.x;
    const int wave = t >> 6, lane = t & 63;
    const int quad = lane >> 4, l15 = lane & 15;
    const int rowBase = blockIdx.x * 64;

    f32x4 acc[4][NT];
#pragma unroll
    for (int mi = 0; mi < 4; ++mi)
#pragma unroll
        for (int ni = 0; ni < NT; ++ni)
            acc[mi][ni] = (f32x4){0.f, 0.f, 0.f, 0.f};

    const int ar = t >> 2;             // A-stage row 0..63
    const int ak = (t & 3) << 3;       // A-stage k seg 0,8,16,24
    const int bc = (t * NCH) >> 2;     // B-stage column
    const int bks = (t * NCH) & 3;     // B-stage starting chunk

    for (int it = 0; it < ITERS; ++it) {
        // ---- stage A (fp32 -> fp16)
        {
            int gr = rowBase + ar;
            float f[8] = {0.f, 0.f, 0.f, 0.f, 0.f, 0.f, 0.f, 0.f};
            if (gr < M) {
                const float* ap = A + (size_t)gr * K + it * 32 + ak;
                float4 v0 = *(const float4*)ap;
                float4 v1 = *(const float4*)(ap + 4);
                f[0] = v0.x; f[1] = v0.y; f[2] = v0.z; f[3] = v0.w;
                f[4] = v1.x; f[5] = v1.y; f[6] = v1.z; f[7] = v1.w;
            }
            f16x8 hv;
#pragma unroll
            for (int j = 0; j < 8; ++j) hv[j] = (_Float16)f[j];
            *(f16x8*)&As[ar * 40 + ak] = hv;
        }
        // ---- stage B (pre-converted fp16, contiguous copy)
        {
            const _Float16* bp = BT + (size_t)bc * K + it * 32 + bks * 8;
            unsigned short* dp = &Bs[bc * 40 + bks * 8];
#pragma unroll
            for (int j = 0; j < NCH; ++j)
                *(f16x8*)(dp + j * 8) = *(const f16x8*)(bp + j * 8);
        }
        __syncthreads();
        f16x8 af[4], bfr[NT];
#pragma unroll
        for (int mi = 0; mi < 4; ++mi)
            af[mi] = *(const f16x8*)&As[(mi * 16 + l15) * 40 + quad * 8];
#pragma unroll
        for (int ni = 0; ni < NT; ++ni)
            bfr[ni] = *(const f16x8*)&Bs[(wave * WN + ni * 16 + l15) * 40 + quad * 8];
#pragma unroll
        for (int mi = 0; mi < 4; ++mi)
#pragma unroll
            for (int ni = 0; ni < NT; ++ni)
                acc[mi][ni] = __builtin_amdgcn_mfma_f32_16x16x32_f16(
                    af[mi], bfr[ni], acc[mi][ni], 0, 0, 0);
        __syncthreads();
    }
    // ---- epilogue: fp16 store + logits. D layout col=lane&15, row=quad*4+reg
    float asv[NT], adv[NT];
#pragma unroll
    for (int ni = 0; ni < NT; ++ni) {
        int col = wave * WN + ni * 16 + l15;
        asv[ni] = att_s[col];
        adv[ni] = att_d[col];
    }
#pragma unroll
    for (int mi = 0; mi < 4; ++mi) {
#pragma unroll
        for (int r = 0; r < 4; ++r) {
            int row = rowBase + mi * 16 + quad * 4 + r;
            bool ok = row < M;
            float ss = 0.f, sd = 0.f;
#pragma unroll
            for (int ni = 0; ni < NT; ++ni) {
                float v = acc[mi][ni][r];
                ss += v * asv[ni];
                sd += v * adv[ni];
                if (ok)
                    HB[(size_t)row * N + wave * WN + ni * 16 + l15] = (_Float16)v;
            }
#pragma unroll
            for (int off = 8; off > 0; off >>= 1) {
                ss += __shfl_xor(ss, off);
                sd += __shfl_xor(sd, off);
            }
            if (ok && l15 == 0) {
                if (H == 4) {
                    aS[row * 4 + wave] = ss;
                    aD[row * 4 + wave] = sd;
                } else {
                    atomicAdd(&aS[row], ss);
                    atomicAdd(&aD[row], sd);
                }
            }
        }
    }
}

// =================== CSR build (dst-bucketed edge list) =========================
__global__ void count_k(const int* __restrict__ dst, int* __restrict__ counts, int E, int Nn)
{
    int e = blockIdx.x * blockDim.x + threadIdx.x;
    if (e >= E + Nn) return;
    int d = (e < E) ? dst[e] : (e - E);
    atomicAdd(&counts[d], 1);
}

__global__ void scan1_k(const int* __restrict__ counts, int* __restrict__ partial,
                        int* __restrict__ bsum, int Nn)
{
    __shared__ int sh[256];
    int i = blockIdx.x * 256 + threadIdx.x;
    int v = (i < Nn) ? counts[i] : 0;
    sh[threadIdx.x] = v;
    __syncthreads();
#pragma unroll
    for (int o = 1; o < 256; o <<= 1) {
        int t = (threadIdx.x >= o) ? sh[threadIdx.x - o] : 0;
        __syncthreads();
        sh[threadIdx.x] += t;
        __syncthreads();
    }
    if (i < Nn) partial[i] = sh[threadIdx.x] - v;
    if (threadIdx.x == 255) bsum[blockIdx.x] = sh[255];
}

__global__ void scan2_k(int* __restrict__ bsum, int nb)
{
    __shared__ int sh[256];
    int v = (threadIdx.x < nb) ? bsum[threadIdx.x] : 0;
    sh[threadIdx.x] = v;
    __syncthreads();
#pragma unroll
    for (int o = 1; o < 256; o <<= 1) {
        int t = (threadIdx.x >= o) ? sh[threadIdx.x - o] : 0;
        __syncthreads();
        sh[threadIdx.x] += t;
        __syncthreads();
    }
    if (threadIdx.x < nb) bsum[threadIdx.x] = sh[threadIdx.x] - v;
}

__global__ void scan3_k(const int* __restrict__ partial, const int* __restrict__ bsum,
                        int* __restrict__ rowptr, int* __restrict__ cursor, int Nn, int ET)
{
    int i = blockIdx.x * 256 + threadIdx.x;
    if (i < Nn) {
        int v = partial[i] + bsum[i >> 8];
        rowptr[i] = v;
        cursor[i] = v;
    }
    if (i == Nn) rowptr[Nn] = ET;
}

__global__ void build_k(const int* __restrict__ src, const int* __restrict__ dst,
                        int* __restrict__ cursor, int* __restrict__ esrc, int E, int Nn)
{
    int e = blockIdx.x * blockDim.x + threadIdx.x;
    if (e >= E + Nn) return;
    int s, d;
    if (e < E) { s = src[e]; d = dst[e]; } else { s = e - E; d = s; }
    int pos = atomicAdd(&cursor[d], 1);
    esrc[pos] = s;
}

// ===== gather layer 1, fp16 h, online softmax, 8-edge unroll ===================
__global__ void gather1_k(const int* __restrict__ rp, const int* __restrict__ esrc,
                          const _Float16* __restrict__ hb, const float* __restrict__ aS,
                          const float* __restrict__ aD, const float* __restrict__ bias,
                          float* __restrict__ out, int Nn)
{
    int d = blockIdx.x * 4 + (threadIdx.x >> 6);
    int lane = threadIdx.x & 63;
    if (d >= Nn) return;
    int c4 = lane << 2;
    int head = lane >> 4;
    int p0 = rp[d], p1 = rp[d + 1];
    float adh = aD[d * 4 + head];
    const float* aSh = aS + head;
    float m = -1e30f, den = 0.f;
    float ax = 0.f, ay = 0.f, az = 0.f, aw = 0.f;
    int p = p0;
    for (; p + 8 <= p1; p += 8) {
        int s[8];
        float l[8];
#pragma unroll
        for (int j = 0; j < 8; ++j) s[j] = esrc[p + j];
#pragma unroll
        for (int j = 0; j < 8; ++j) l[j] = lrelu(aSh[s[j] * 4] + adh);
        float lm = l[0];
#pragma unroll
        for (int j = 1; j < 8; ++j) lm = fmaxf(lm, l[j]);
        if (lm > m) {
            float r = __expf(m - lm);
            ax *= r; ay *= r; az *= r; aw *= r; den *= r;
            m = lm;
        }
        h16x4 v[8];
#pragma unroll
        for (int j = 0; j < 8; ++j) v[j] = *(const h16x4*)&hb[(size_t)s[j] * 256 + c4];
#pragma unroll
        for (int j = 0; j < 8; ++j) {
            float w = __expf(l[j] - m);
            den += w;
            ax += (float)v[j][0] * w;
            ay += (float)v[j][1] * w;
            az += (float)v[j][2] * w;
            aw += (float)v[j][3] * w;
        }
    }
    for (; p < p1; ++p) {
        int s0 = esrc[p];
        float l0 = lrelu(aSh[s0 * 4] + adh);
        if (l0 > m) {
            float r = __expf(m - l0);
            ax *= r; ay *= r; az *= r; aw *= r; den *= r;
            m = l0;
        }
        float w0 = __expf(l0 - m);
        den += w0;
        h16x4 v0 = *(const h16x4*)&hb[(size_t)s0 * 256 + c4];
        ax += (float)v0[0] * w0; ay += (float)v0[1] * w0;
        az += (float)v0[2] * w0; aw += (float)v0[3] * w0;
    }
    float inv = 1.f / (den + 1e-16f);
    float4 b4 = *(const float4*)&bias[c4];
    float4 r;
    r.x = ax * inv + b4.x; r.x = r.x > 0.f ? r.x : expm1f(r.x);
    r.y = ay * inv + b4.y; r.y = r.y > 0.f ? r.y : expm1f(r.y);
    r.z = az * inv + b4.z; r.z = r.z > 0.f ? r.z : expm1f(r.z);
    r.w = aw * inv + b4.w; r.w = r.w > 0.f ? r.w : expm1f(r.w);
    *(float4*)&out[(size_t)d * 256 + c4] = r;
}

// ===== gather layer 2, fp16 h, online softmax, half-waves, 4-edge unroll =======
__global__ void gather2_k(const int* __restrict__ rp, const int* __restrict__ esrc,
                          const _Float16* __restrict__ hb, const float* __restrict__ aS,
                          const float* __restrict__ aD, float* __restrict__ out, int Nn)
{
    int d = blockIdx.x * 4 + (threadIdx.x >> 6);
    int lane = threadIdx.x & 63;
    if (d >= Nn) return;
    int half = lane >> 5;
    int c4 = (lane & 31) << 2;
    int p0 = rp[d], p1 = rp[d + 1];
    float adh = aD[d];
    float m = -1e30f, den = 0.f;
    float ax = 0.f, ay = 0.f, az = 0.f, aw = 0.f;
    int p = p0 + half;
    for (; p + 6 < p1; p += 8) {
        int s[4];
        float l[4];
#pragma unroll
        for (int j = 0; j < 4; ++j) s[j] = esrc[p + 2 * j];
#pragma unroll
        for (int j = 0; j < 4; ++j) l[j] = lrelu(aS[s[j]] + adh);
        float lm = fmaxf(fmaxf(l[0], l[1]), fmaxf(l[2], l[3]));
        if (lm > m) {
            float r = __expf(m - lm);
            ax *= r; ay *= r; az *= r; aw *= r; den *= r;
            m = lm;
        }
        h16x4 v[4];
#pragma unroll
        for (int j = 0; j < 4; ++j) v[j] = *(const h16x4*)&hb[(size_t)s[j] * 128 + c4];
#pragma unroll
        for (int j = 0; j < 4; ++j) {
            float w = __expf(l[j] - m);
            den += w;
            ax += (float)v[j][0] * w;
            ay += (float)v[j][1] * w;
            az += (float)v[j][2] * w;
            aw += (float)v[j][3] * w;
        }
    }
    for (; p < p1; p += 2) {
        int s0 = esrc[p];
        float l0 = lrelu(aS[s0] + adh);
        if (l0 > m) {
            float r = __expf(m - l0);
            ax *= r; ay *= r; az *= r; aw *= r; den *= r;
            m = l0;
        }
        float w0 = __expf(l0 - m);
        den += w0;
        h16x4 v0 = *(const h16x4*)&hb[(size_t)s0 * 128 + c4];
        ax += (float)v0[0] * w0; ay += (float)v0[1] * w0;
        az += (float)v0[2] * w0; aw += (float)v0[3] * w0;
    }
    // merge halves: rescale to common max, then sum
    float mo = __shfl_xor(m, 32);
    float mm = fmaxf(m, mo);
    float fsc = __expf(m - mm);
    ax *= fsc; ay *= fsc; az *= fsc; aw *= fsc; den *= fsc;
    ax += __shfl_xor(ax, 32);
    ay += __shfl_xor(ay, 32);
    az += __shfl_xor(az, 32);
    aw += __shfl_xor(aw, 32);
    den += __shfl_xor(den, 32);
    float inv = 1.f / (den + 1e-16f);
    if (half == 0)
        *(float4*)&out[(size_t)d * 128 + c4] =
            make_float4(ax * inv, ay * inv, az * inv, aw * inv);
}

// batch is sorted; per-block run-length accumulate then atomicAdd per graph run
__global__ void pool_k(const float* __restrict__ o2, const float* __restrict__ b2,
                       const int* __restrict__ batch, float* __restrict__ sums, int Nn, int C)
{
    int c = threadIdx.x;               // C = 128
    int n0 = blockIdx.x * 64;
    int n1 = min(n0 + 64, Nn);
    float local = 0.f;
    int gcur = batch[n0];
    float bc = b2[c];
    for (int n = n0; n < n1; ++n) {
        int g = batch[n];
        if (g != gcur) {
            atomicAdd(&sums[gcur * C + c], local);
            local = 0.f;
            gcur = g;
        }
        float v = o2[(size_t)n * C + c] + bc;
        local += v > 0.f ? v : expm1f(v);
    }
    atomicAdd(&sums[gcur * C + c], local);
}

__global__ void final_k(const float* __restrict__ sums, const int* __restrict__ batch,
                        const float* __restrict__ lin_w, const float* __restrict__ lin_b,
                        float* __restrict__ out, int Nn, int G, int C, int NC)
{
    __shared__ float inv[64];
    int t = threadIdx.x;
    if (t < G) {
        int lo = 0, hi = Nn;
        while (lo < hi) { int mid = (lo + hi) >> 1; if (batch[mid] < t) lo = mid + 1; else hi = mid; }
        int lb = lo;
        lo = 0; hi = Nn;
        while (lo < hi) { int mid = (lo + hi) >> 1; if (batch[mid] < t + 1) lo = mid + 1; else hi = mid; }
        int cnt = lo - lb;
        inv[t] = 1.f / fmaxf((float)cnt, 1.f);
    }
    __syncthreads();
    if (t < G * NC) {
        int g = t / NC, k = t % NC;
        float acc = 0.f;
        for (int c = 0; c < C; ++c) acc += sums[g * C + c] * lin_w[c * NC + k];
        out[t] = acc * inv[g] + lin_b[k];
    }
}

extern "C" void kernel_launch(void* const* d_in, const int* in_sizes, int n_in,
                              void* d_out, int out_size, void* d_ws, size_t ws_size,
                              hipStream_t stream)
{
    const float* x      = (const float*)d_in[0];
    const int*   eidx   = (const int*)d_in[1];
    const int*   batch  = (const int*)d_in[2];
    const float* W1     = (const float*)d_in[3];
    const float* att_s1 = (const float*)d_in[4];
    const float* att_d1 = (const float*)d_in[5];
    const float* b1     = (const float*)d_in[6];
    const float* W2     = (const float*)d_in[7];
    const float* att_s2 = (const float*)d_in[8];
    const float* att_d2 = (const float*)d_in[9];
    const float* b2     = (const float*)d_in[10];
    const float* lin_w  = (const float*)d_in[11];
    const float* lin_b  = (const float*)d_in[12];

    const int Nn  = in_sizes[2];         // 50000
    const int E   = in_sizes[1] / 2;     // 800000
    const int H1_ = 4, C1_ = 64, C2_ = 128, G = 32, NC = 5;
    const int D1 = H1_ * C1_;            // 256
    const int ET = E + Nn;

    const int* srcp = eidx;
    const int* dstp = eidx + E;

    float* ws = (float*)d_ws;
    size_t off = 0;
    auto alloc = [&](size_t n) { float* p = ws + off; off += n; return p; };
    float* o1   = alloc((size_t)Nn * D1);
    float* o2   = alloc((size_t)Nn * C2_);
    float* aS1  = alloc((size_t)Nn * H1_);
    float* aD1  = alloc((size_t)Nn * H1_);
    float* aS2  = alloc(Nn);              // contiguous with aD2 for single memset
    float* aD2  = alloc(Nn);
    float* sums = alloc((size_t)G * C2_);
    _Float16* BT1 = (_Float16*)alloc(D1 * 128 / 2);           // [256][128] fp16
    _Float16* BT2 = (_Float16*)alloc(C2_ * 256 / 2);          // [128][256] fp16
    _Float16* hb1 = (_Float16*)alloc((size_t)Nn * D1 / 2);    // fp16 h1
    _Float16* hb2 = (_Float16*)alloc((size_t)Nn * C2_ / 2);   // fp16 h2
    int* iws    = (int*)(ws + off);
    int* counts = iws;
    int* partial= iws + Nn;
    int* rowptr = iws + 2 * Nn;
    int* cursor = iws + 3 * Nn + 1;
    int* bsum   = iws + 4 * Nn + 1;
    int* esrc   = iws + 4 * Nn + 1 + 256;

    const int NB = (Nn + 255) / 256;
    const int GB = (Nn + 63) / 64;

    // ---------------- CSR build (shared by both layers) ----------------
    hipMemsetAsync(counts, 0, (size_t)Nn * 4, stream);
    hipMemsetAsync(aS2, 0, (size_t)2 * Nn * 4, stream);   // aS2+aD2 (gemm2 atomics)
    count_k<<<(ET + 255) / 256, 256, 0, stream>>>(dstp, counts, E, Nn);
    scan1_k<<<NB, 256, 0, stream>>>(counts, partial, bsum, Nn);
    scan2_k<<<1, 256, 0, stream>>>(bsum, NB);
    scan3_k<<<(Nn + 256) / 256, 256, 0, stream>>>(partial, bsum, rowptr, cursor, Nn, ET);
    build_k<<<(ET + 255) / 256, 256, 0, stream>>>(srcp, dstp, cursor, esrc, E, Nn);

    // ---------------- weight transpose+convert (fp16) ----------------
    convW_k<<<256, 256, 0, stream>>>(W1, W2, BT1, BT2);

    // ---------------- layer 1: fp16 GEMM + fp16 out + logits fused ----------------
    gemm_fused<256, 128, 4><<<GB, 256, 0, stream>>>(x, BT1, hb1, att_s1, att_d1,
                                                    aS1, aD1, Nn);
    gather1_k<<<(Nn + 3) / 4, 256, 0, stream>>>(rowptr, esrc, hb1, aS1, aD1, b1, o1, Nn);

    // ---------------- layer 2: fp16 GEMM + fp16 out + logits fused ----------------
    gemm_fused<128, 256, 1><<<GB, 256, 0, stream>>>(o1, BT2, hb2, att_s2, att_d2,
                                                    aS2, aD2, Nn);
    gather2_k<<<(Nn + 3) / 4, 256, 0, stream>>>(rowptr, esrc, hb2, aS2, aD2, o2, Nn);

    // ---------------- pool + classifier ----------------
    hipMemsetAsync(sums, 0, (size_t)G * C2_ * 4, stream);
    pool_k<<<GB, C2_, 0, stream>>>(o2, b2, batch, sums, Nn, C2_);
    final_k<<<1, 256, 0, stream>>>(sums, batch, lin_w, lin_b, (float*)d_out, Nn, G, C2_, NC);
}